// Round 12
// baseline (211.673 us; speedup 1.0000x reference)
//
#include <hip/hip_runtime.h>
#include <hip/hip_bf16.h>
#include <stdint.h>

namespace {

constexpr int T_LEN = 2048;
constexpr int NROWS = 192;       // 3*64 rows per head
constexpr int QBLK  = 128;       // t-columns per block (R12: doubled)
constexpr int NBH   = 32;        // 2 batches * 16 heads
constexpr int KT_STRIDE = 72;    // padded row stride (bf16 elems) — R1/R3-validated
constexpr int TILE_ELEMS = 64 * KT_STRIDE;   // 4608 elems = 9216 B per 64-tile
constexpr int TILE_BYTES = TILE_ELEMS * 2;   // 9216 B = 9 chunks of 1024

typedef float f32x4 __attribute__((ext_vector_type(4)));
typedef short bf16x8 __attribute__((ext_vector_type(8)));
typedef short bf16x4 __attribute__((ext_vector_type(4)));

__device__ __forceinline__ unsigned short f2bf(float f) {
  union { float f; unsigned u; } v; v.f = f;
  unsigned r = v.u + 0x7fffu + ((v.u >> 16) & 1u);   // RNE
  return (unsigned short)(r >> 16);
}
__device__ __forceinline__ unsigned pack2(float a, float b) {
  return (unsigned)f2bf(a) | ((unsigned)f2bf(b) << 16);
}
__device__ __forceinline__ float fast_exp2(float x) {
#if __has_builtin(__builtin_amdgcn_exp2f)
  return __builtin_amdgcn_exp2f(x);
#else
  return exp2f(x);
#endif
}
__device__ __forceinline__ f32x4 mfma_16x16x16_bf16(bf16x4 a, bf16x4 b, f32x4 c) {
#if __has_builtin(__builtin_amdgcn_mfma_f32_16x16x16bf16_1k)
  return __builtin_amdgcn_mfma_f32_16x16x16bf16_1k(a, b, c, 0, 0, 0);
#else
  asm("v_mfma_f32_16x16x16_bf16 %0, %1, %2, %0" : "+v"(c) : "v"(a), "v"(b));
  return c;
#endif
}
// Async global->LDS DMA, 16B per lane: LDS dest = wave-uniform base + lane*16.
__device__ __forceinline__ void gload_lds16(const void* g, void* l) {
  __builtin_amdgcn_global_load_lds(
      (const __attribute__((address_space(1))) unsigned int*)g,
      (__attribute__((address_space(3))) unsigned int*)l, 16, 0, 0);
}

} // namespace

// Normalize mask to uint8 (fallback path). Stride detect via guaranteed-true mask[0][1].
__global__ void nm_kernel(const unsigned char* __restrict__ raw,
                          unsigned char* __restrict__ outm, int n) {
  int stride = (raw[1] != 0) ? 1 : ((raw[4] != 0) ? 4 : 8);
  int i = blockIdx.x * blockDim.x + threadIdx.x;
  if (i < n) outm[i] = (raw[(size_t)i * stride] != 0) ? 1 : 0;
}

// ---------------- merged prepass: Q|K|V conversion + bias table, ONE launch --------
// grid (32, NBH, 4), 256 thr.
// z==0: Q -> [bh][t][64] linear, scaled 0.125*log2(e), masked-t rows zeroed.
// z==1: K -> [bh][sb][64][72] tiles.
// z>=2: V -> [bh][sb][64][72] tiles (cv3 mapping, 64 blocks/bh via z,bx);
//        z==2, bh==0, bx<24 blocks additionally emit the bias table
//        (mask_elems entries {0,-1e30} + T_LEN zero row).
__global__ __launch_bounds__(256) void prep12_kernel(const float* __restrict__ qkv,
                                                     const unsigned char* __restrict__ mraw,
                                                     short* __restrict__ qtg,
                                                     short* __restrict__ ktg,
                                                     short* __restrict__ vtg,
                                                     float* __restrict__ bias,
                                                     int mask_elems) {
  const int z  = blockIdx.z;
  const int bh = blockIdx.y;
  const int bx = blockIdx.x;
  const int t  = threadIdx.x;

  if (z >= 2) {
    // V conversion (cv3-verbatim mapping)
    int cid = ((bh * 64) + (z - 2) * 32 + bx) * 256 + t;
    int bh2 = cid >> 14;
    int rem = cid & 16383;
    int c = rem >> 8;
    int cg = rem & 255;
    int grp = cg >> 3, jin = cg & 7;
    const float* src = qkv + (size_t)bh2 * NROWS * T_LEN + (size_t)(128 + c) * T_LEN + cg * 8;
    float4 a = *(const float4*)src;
    float4 b = *(const float4*)(src + 4);
    bf16x4 o0, o1;
    o0[0] = (short)f2bf(a.x); o0[1] = (short)f2bf(a.y);
    o0[2] = (short)f2bf(a.z); o0[3] = (short)f2bf(a.w);
    o1[0] = (short)f2bf(b.x); o1[1] = (short)f2bf(b.y);
    o1[2] = (short)f2bf(b.z); o1[3] = (short)f2bf(b.w);
    short* d = vtg + (size_t)(bh2 * 32 + grp) * TILE_ELEMS + c * KT_STRIDE + jin * 8;
    *(bf16x4*)d = o0;
    *(bf16x4*)(d + 4) = o1;
    // bias table (once, by 24 designated blocks)
    if (z == 2 && bh == 0 && bx < 24) {
      int i = bx * 256 + t;            // 0..6143 = mask_elems + T_LEN
      int stride = (mraw[1] != 0) ? 1 : ((mraw[4] != 0) ? 4 : 8);
      if (i < mask_elems) bias[i] = (mraw[(size_t)i * stride] != 0) ? 0.0f : -1.0e30f;
      else if (i < mask_elems + T_LEN) bias[i] = 0.0f;
    }
    return;
  }

  // Q/K transpose through LDS (tq9-verbatim)
  __shared__ float tile[64][65];
  const int s0 = bx * 64;
  const float* src = qkv + (size_t)bh * NROWS * T_LEN + (size_t)z * 64 * T_LEN;
  const int c = t >> 2;
  #pragma unroll
  for (int p = 0; p < 4; ++p) {
    int col = (t & 3) * 4 + p * 16;
    float4 v = *(const float4*)&src[(size_t)c * T_LEN + s0 + col];
    tile[c][col] = v.x; tile[c][col + 1] = v.y;
    tile[c][col + 2] = v.z; tile[c][col + 3] = v.w;
  }
  __syncthreads();
  const int s = t & 63;
  float scale;
  if (z) {
    scale = 1.0f;
  } else {
    const int mstride = (mraw[1] != 0) ? 1 : ((mraw[4] != 0) ? 4 : 8);
    const int nb = bh >> 4;
    const bool live = mraw[((size_t)nb * T_LEN + s0 + s) * mstride] != 0;
    scale = live ? 0.18033688011112042f : 0.0f;   // 0.125*log2(e), 0 for masked t
  }
  #pragma unroll
  for (int p = 0; p < 2; ++p) {
    int jc = (t >> 6) * 2 + p;
    bf16x4 o0, o1;
    #pragma unroll
    for (int i = 0; i < 4; ++i) {
      o0[i] = (short)f2bf(tile[jc * 8 + i][s] * scale);
      o1[i] = (short)f2bf(tile[jc * 8 + 4 + i][s] * scale);
    }
    short* d = z
      ? (ktg + (size_t)(bh * 32 + bx) * TILE_ELEMS + s * KT_STRIDE + jc * 8)
      : (qtg + (size_t)bh * T_LEN * 64 + (size_t)(s0 + s) * 64 + jc * 8);
    *(bf16x4*)d = o0;
    *(bf16x4*)(d + 4) = o1;
  }
}

// ------ attn12: R11 per-wave code, QBLK=128 via 16-wave blocks. Grid 512 (2/CU).
// Wave wv: sgrp=wv&3 owns st=sgrp; tgrp=wv>>2 owns t-windows {tgrp*32, tgrp*32+16}.
// Per-CU barrier-iterations and staging DMA halve vs R11. 3-round LDS combine tree.

__global__ __launch_bounds__(1024, 8) void attn12_kernel(const short* __restrict__ qtg,
                                                         const short* __restrict__ ktg,
                                                         const short* __restrict__ vtg,
                                                         const float* __restrict__ bias,
                                                         int mask_elems,
                                                         float* __restrict__ out) {
  __shared__ __align__(16) short smem[4 * TILE_ELEMS];   // K0|K1|V0|V1 (36864 B)

  const int tid  = threadIdx.x;
  const int lane = tid & 63;
  const int wv   = tid >> 6;    // 0..15
  const int sgrp = wv & 3;      // owns st = sgrp
  const int tgrp = wv >> 2;     // 0..3 — owns t-windows {tgrp*32, tgrp*32+16}
  const int l15  = lane & 15;
  const int g    = lane >> 4;

  int id = blockIdx.x;
  id = (id & 7) * 64 + (id >> 3);    // bijective XCD swizzle over 512 blocks
  const int bh = id >> 4;
  const int t0 = (id & 15) * QBLK;
  const int nb = bh >> 4;

  // two t-columns per wave
  const int tA = t0 + tgrp * 32 + l15;
  const int tB = tA + 16;

  // Q fragments (masked-t rows pre-zeroed by prep12)
  const short* Qbase = qtg + (size_t)bh * T_LEN * 64;
  const bf16x8 qfA0 = *(const bf16x8*)(Qbase + (size_t)tA * 64 + g * 8);
  const bf16x8 qfA1 = *(const bf16x8*)(Qbase + (size_t)tA * 64 + 32 + g * 8);
  const bf16x8 qfB0 = *(const bf16x8*)(Qbase + (size_t)tB * 64 + g * 8);
  const bf16x8 qfB1 = *(const bf16x8*)(Qbase + (size_t)tB * 64 + 32 + g * 8);

  // per-tw bias row: live t -> batch row; masked t -> zero row (uniform softmax)
  const float btA = bias[(size_t)nb * T_LEN + tA];
  const float btB = bias[(size_t)nb * T_LEN + tB];
  const float* __restrict__ browA = bias + ((btA != 0.0f) ? (size_t)mask_elems
                                                          : (size_t)nb * T_LEN);
  const float* __restrict__ browB = bias + ((btB != 0.0f) ? (size_t)mask_elems
                                                          : (size_t)nb * T_LEN);

  const char* __restrict__ kt0 = (const char*)(ktg + (size_t)bh * 32 * TILE_ELEMS);
  const char* __restrict__ vt0 = (const char*)(vtg + (size_t)bh * 32 * TILE_ELEMS);
  char* KtL = (char*)smem;
  char* VsL = (char*)(smem + 2 * TILE_ELEMS);

  // DMA chunk assignment over 16 waves: K chunks 0-8 -> waves 0-8;
  // V chunks 0-6 -> waves 9-15; V chunks 7,8 -> waves 0,1. (9+9 = 18 x 1024 B)
  {
    if (wv < 9)  gload_lds16(kt0 + wv * 1024 + lane * 16, KtL + wv * 1024);
    if (wv >= 9) gload_lds16(vt0 + (wv - 9) * 1024 + lane * 16, VsL + (wv - 9) * 1024);
    if (wv < 2)  gload_lds16(vt0 + (7 + wv) * 1024 + lane * 16, VsL + (7 + wv) * 1024);
  }
  __syncthreads();                     // drains DMA (vmcnt) + joins waves

  f32x4 accA[4], accB[4];
  #pragma unroll
  for (int i = 0; i < 4; ++i) { accA[i] = (f32x4){0.f,0.f,0.f,0.f}; accB[i] = accA[i]; }
  float lA = 0.0f, lB = 0.0f;

  const int koff = (sgrp * 16 + l15) * KT_STRIDE;
  const int boff = sgrp * 16 + g * 4;

  int cur = 0;
  for (int sb = 0; sb < T_LEN / 64; ++sb) {
    if (sb + 1 < T_LEN / 64) {
      const char* ks = kt0 + (size_t)(sb + 1) * TILE_BYTES;
      const char* vs = vt0 + (size_t)(sb + 1) * TILE_BYTES;
      char* Ktn = KtL + (cur ^ 1) * TILE_BYTES;
      char* Vsn = VsL + (cur ^ 1) * TILE_BYTES;
      if (wv < 9)  gload_lds16(ks + wv * 1024 + lane * 16, Ktn + wv * 1024);
      if (wv >= 9) gload_lds16(vs + (wv - 9) * 1024 + lane * 16, Vsn + (wv - 9) * 1024);
      if (wv < 2)  gload_lds16(vs + (7 + wv) * 1024 + lane * 16, Vsn + (7 + wv) * 1024);
    }

    const short* Ktc = smem + cur * TILE_ELEMS;
    const short* Vsc = smem + (2 + cur) * TILE_ELEMS;

    // K fragment read ONCE per wave, shared by both t-windows
    bf16x8 kf0 = *(const bf16x8*)&Ktc[koff + g * 8];
    bf16x8 kf1 = *(const bf16x8*)&Ktc[koff + 32 + g * 8];

    __builtin_amdgcn_s_setprio(1);
    f32x4 SA = (f32x4){0.f, 0.f, 0.f, 0.f};
    SA = __builtin_amdgcn_mfma_f32_16x16x32_bf16(kf0, qfA0, SA, 0, 0, 0);
    SA = __builtin_amdgcn_mfma_f32_16x16x32_bf16(kf1, qfA1, SA, 0, 0, 0);
    f32x4 SB = (f32x4){0.f, 0.f, 0.f, 0.f};
    SB = __builtin_amdgcn_mfma_f32_16x16x32_bf16(kf0, qfB0, SB, 0, 0, 0);
    SB = __builtin_amdgcn_mfma_f32_16x16x32_bf16(kf1, qfB1, SB, 0, 0, 0);
    __builtin_amdgcn_s_setprio(0);

    const f32x4 b4A = *(const f32x4*)&browA[sb * 64 + boff];
    const f32x4 b4B = *(const f32x4*)&browB[sb * 64 + boff];
    float pA0 = fast_exp2(SA[0] + b4A[0]);
    float pA1 = fast_exp2(SA[1] + b4A[1]);
    float pA2 = fast_exp2(SA[2] + b4A[2]);
    float pA3 = fast_exp2(SA[3] + b4A[3]);
    lA += (pA0 + pA1) + (pA2 + pA3);
    float pB0 = fast_exp2(SB[0] + b4B[0]);
    float pB1 = fast_exp2(SB[1] + b4B[1]);
    float pB2 = fast_exp2(SB[2] + b4B[2]);
    float pB3 = fast_exp2(SB[3] + b4B[3]);
    lB += (pB0 + pB1) + (pB2 + pB3);

    union { bf16x4 v; __hip_bfloat162 h[2]; } pfA, pfB;
    pfA.h[0] = __float22bfloat162_rn(float2{pA0, pA1});
    pfA.h[1] = __float22bfloat162_rn(float2{pA2, pA3});
    pfB.h[0] = __float22bfloat162_rn(float2{pB0, pB1});
    pfB.h[1] = __float22bfloat162_rn(float2{pB2, pB3});

    __builtin_amdgcn_s_setprio(1);
    #pragma unroll
    for (int cb = 0; cb < 4; ++cb) {
      bf16x4 vf = *(const bf16x4*)&Vsc[(cb * 16 + l15) * KT_STRIDE + sgrp * 16 + g * 4];
      accA[cb] = mfma_16x16x16_bf16(vf, pfA.v, accA[cb]);
      accB[cb] = mfma_16x16x16_bf16(vf, pfB.v, accB[cb]);
    }
    __builtin_amdgcn_s_setprio(0);

    __syncthreads();                   // reads of buf[cur] done; DMA into buf[cur^1] drained
    cur ^= 1;
  }

  // ---- 4-partial combine over sgrp: 3 sequential pair-rounds, 4 slots (36864 B).
  // Slot[tgrp]: 64 lanes x 36 floats (32 acc + 2 l + pad).
  float* scr = (float*)smem;
  const int lb = tgrp * 2304 + lane * 36;
  #define DUMP_ROW  { float* b_ = scr + lb;                                   \
      _Pragma("unroll") for (int cb = 0; cb < 4; ++cb) {                      \
        *(f32x4*)&b_[cb * 4] = accA[cb]; *(f32x4*)&b_[16 + cb * 4] = accB[cb];} \
      b_[32] = lA; b_[33] = lB; }
  #define ADD_ROW   { const float* b_ = scr + lb;                             \
      _Pragma("unroll") for (int cb = 0; cb < 4; ++cb) {                      \
        accA[cb] += *(const f32x4*)&b_[cb * 4];                               \
        accB[cb] += *(const f32x4*)&b_[16 + cb * 4]; }                        \
      lA += b_[32]; lB += b_[33]; }
  if (sgrp == 3) DUMP_ROW
  __syncthreads();
  if (sgrp == 1) ADD_ROW           // 1 += 3
  __syncthreads();
  if (sgrp == 2) DUMP_ROW
  __syncthreads();
  if (sgrp == 0) ADD_ROW           // 0 += 2
  __syncthreads();
  if (sgrp == 1) DUMP_ROW          // holds 1+3
  __syncthreads();
  if (sgrp == 0) {
    ADD_ROW                        // 0+2+1+3
    lA += __shfl_xor(lA, 16, 64);
    lA += __shfl_xor(lA, 32, 64);
    lB += __shfl_xor(lB, 16, 64);
    lB += __shfl_xor(lB, 32, 64);
    const float ilA = 1.0f / lA;
    const float ilB = 1.0f / lB;
    const size_t out_base = (size_t)bh * 64 * T_LEN;
    #pragma unroll
    for (int cb = 0; cb < 4; ++cb) {
      #pragma unroll
      for (int r = 0; r < 4; ++r) {
        int c = cb * 16 + g * 4 + r;
        out[out_base + (size_t)c * T_LEN + tA] = accA[cb][r] * ilA;
        out[out_base + (size_t)c * T_LEN + tB] = accB[cb][r] * ilB;
      }
    }
  }
  #undef DUMP_ROW
  #undef ADD_ROW
}

// ---------------- fallback path (round-1 kernel, used if ws too small) ------------

__global__ __launch_bounds__(256) void attn_fb_kernel(const float* __restrict__ qkv,
                                                      const unsigned char* __restrict__ maskn,
                                                      float* __restrict__ out) {
  __shared__ __align__(16) short Kt[64 * KT_STRIDE];
  __shared__ __align__(16) short Vs[64 * KT_STRIDE];
  __shared__ __align__(16) unsigned char Ms[T_LEN];

  const int tid  = threadIdx.x;
  const int lane = tid & 63;
  const int wv   = tid >> 6;
  const int l15  = lane & 15;
  const int g    = lane >> 4;

  const int bh = blockIdx.y;
  const int nb = bh >> 4;
  const int t0 = blockIdx.x * 64;

  const float* __restrict__ Qg = qkv + (size_t)bh * NROWS * T_LEN;
  const float* __restrict__ Kg = Qg + (size_t)64 * T_LEN;
  const float* __restrict__ Vg = Qg + (size_t)128 * T_LEN;

  {
    const uint2* src = (const uint2*)(maskn + (size_t)nb * T_LEN);
    ((uint2*)Ms)[tid] = src[tid];
  }
  {
    const int c2 = (tid >> 6) * 2;
    const int s  = tid & 63;
    #pragma unroll
    for (int p = 0; p < 8; ++p) {
      int c = p * 8 + c2;
      float f0 = Qg[(size_t)c * T_LEN + t0 + s] * 0.125f;
      float f1 = Qg[(size_t)(c + 1) * T_LEN + t0 + s] * 0.125f;
      *(unsigned*)&Kt[s * KT_STRIDE + c] = pack2(f0, f1);
    }
  }
  __syncthreads();

  bf16x8 qf0 = *(const bf16x8*)&Kt[(wv * 16 + l15) * KT_STRIDE + g * 8];
  bf16x8 qf1 = *(const bf16x8*)&Kt[(wv * 16 + l15) * KT_STRIDE + 32 + g * 8];
  const int t_lane = t0 + wv * 16 + l15;
  const bool invt = (Ms[t_lane] == 0);

  f32x4 acc[4];
  #pragma unroll
  for (int i = 0; i < 4; ++i) acc[i] = (f32x4){0.f, 0.f, 0.f, 0.f};
  float m_run = -3.0e38f;
  float l_run = 0.0f;

  for (int sb = 0; sb < T_LEN / 64; ++sb) {
    const int s0 = sb * 64;
    __syncthreads();
    {
      const int c2 = (tid >> 6) * 2;
      const int s  = tid & 63;
      #pragma unroll
      for (int p = 0; p < 8; ++p) {
        int c = p * 8 + c2;
        float f0 = Kg[(size_t)c * T_LEN + s0 + s];
        float f1 = Kg[(size_t)(c + 1) * T_LEN + s0 + s];
        *(unsigned*)&Kt[s * KT_STRIDE + c] = pack2(f0, f1);
      }
    }
    {
      const int cv = (tid >> 5);
      const int s2 = tid & 31;
      #pragma unroll
      for (int p = 0; p < 8; ++p) {
        int c = p * 8 + cv;
        float2 f = *(const float2*)&Vg[(size_t)c * T_LEN + s0 + 2 * s2];
        *(unsigned*)&Vs[c * KT_STRIDE + 2 * s2] = pack2(f.x, f.y);
      }
    }
    __syncthreads();

    #pragma unroll
    for (int st = 0; st < 4; ++st) {
      const int srow = st * 16 + l15;
      bf16x8 kf0 = *(const bf16x8*)&Kt[srow * KT_STRIDE + g * 8];
      bf16x8 kf1 = *(const bf16x8*)&Kt[srow * KT_STRIDE + 32 + g * 8];
      f32x4 S = (f32x4){0.f, 0.f, 0.f, 0.f};
      S = __builtin_amdgcn_mfma_f32_16x16x32_bf16(kf0, qf0, S, 0, 0, 0);
      S = __builtin_amdgcn_mfma_f32_16x16x32_bf16(kf1, qf1, S, 0, 0, 0);

      const unsigned m4 = *(const unsigned*)&Ms[s0 + st * 16 + g * 4];
      float vals[4];
      #pragma unroll
      for (int r = 0; r < 4; ++r) {
        float x = ((m4 >> (8 * r)) & 0xffu) ? S[r] : -1.0e30f;
        vals[r] = invt ? 0.0f : x;
      }
      float pm = fmaxf(fmaxf(vals[0], vals[1]), fmaxf(vals[2], vals[3]));
      pm = fmaxf(pm, __shfl_xor(pm, 16, 64));
      pm = fmaxf(pm, __shfl_xor(pm, 32, 64));
      const float newm = fmaxf(m_run, pm);
      const float alpha = fast_exp2((m_run - newm) * 1.44269504f);
      float p0 = fast_exp2((vals[0] - newm) * 1.44269504f);
      float p1 = fast_exp2((vals[1] - newm) * 1.44269504f);
      float p2 = fast_exp2((vals[2] - newm) * 1.44269504f);
      float p3 = fast_exp2((vals[3] - newm) * 1.44269504f);
      float ps = (p0 + p1) + (p2 + p3);
      ps += __shfl_xor(ps, 16, 64);
      ps += __shfl_xor(ps, 32, 64);
      l_run = l_run * alpha + ps;
      m_run = newm;
      if (__any(alpha < 1.0f)) {
        #pragma unroll
        for (int cb = 0; cb < 4; ++cb)
          #pragma unroll
          for (int r = 0; r < 4; ++r) acc[cb][r] *= alpha;
      }
      bf16x4 pf;
      pf[0] = (short)f2bf(p0); pf[1] = (short)f2bf(p1);
      pf[2] = (short)f2bf(p2); pf[3] = (short)f2bf(p3);
      #pragma unroll
      for (int cb = 0; cb < 4; ++cb) {
        bf16x4 vf = *(const bf16x4*)&Vs[(cb * 16 + l15) * KT_STRIDE + st * 16 + g * 4];
        acc[cb] = mfma_16x16x16_bf16(vf, pf, acc[cb]);
      }
    }
  }

  const float il = 1.0f / l_run;
  const size_t out_base = (size_t)bh * 64 * T_LEN;
  #pragma unroll
  for (int cb = 0; cb < 4; ++cb) {
    #pragma unroll
    for (int r = 0; r < 4; ++r) {
      int c = cb * 16 + g * 4 + r;
      out[out_base + (size_t)c * T_LEN + t_lane] = acc[cb][r] * il;
    }
  }
}

// ---------------- launch ----------------

extern "C" void kernel_launch(void* const* d_in, const int* in_sizes, int n_in,
                              void* d_out, int out_size, void* d_ws, size_t ws_size,
                              hipStream_t stream) {
  (void)n_in; (void)out_size;
  const float* qkv = (const float*)d_in[0];
  const unsigned char* mraw = (const unsigned char*)d_in[1];
  float* out = (float*)d_out;
  const int mask_elems = in_sizes[1];   // 2*2048

  // ws layout: qtg(8 MB) | ktg tiles(9 MB) | vtg tiles(9 MB) | bias((mask_elems+2048)*4)
  const size_t QSZ = (size_t)NBH * T_LEN * 64 * sizeof(short);          // 8388608
  const size_t TSZ = (size_t)NBH * 32 * TILE_ELEMS * sizeof(short);     // 9437184
  const size_t BSZ = (size_t)(mask_elems + T_LEN) * sizeof(float);
  const size_t need = QSZ + 2 * TSZ + BSZ;
  if (ws_size >= need) {
    short* qtg = (short*)d_ws;
    short* ktg = (short*)((char*)d_ws + QSZ);
    short* vtg = (short*)((char*)d_ws + QSZ + TSZ);
    float* bias = (float*)((char*)d_ws + QSZ + 2 * TSZ);
    prep12_kernel<<<dim3(32, NBH, 4), 256, 0, stream>>>(qkv, mraw, qtg, ktg, vtg,
                                                        bias, mask_elems);
    attn12_kernel<<<dim3(NBH * 16), 1024, 0, stream>>>(qtg, ktg, vtg, bias,
                                                       mask_elems, out);
  } else {
    unsigned char* maskn = (unsigned char*)d_ws;
    nm_kernel<<<(mask_elems + 255) / 256, 256, 0, stream>>>(mraw, maskn, mask_elems);
    attn_fb_kernel<<<dim3(T_LEN / 64, NBH), 256, 0, stream>>>(qkv, maskn, out);
  }
}

// Round 13
// 130.457 us; speedup vs baseline: 1.6225x; 1.6225x over previous
//
#include <hip/hip_runtime.h>
#include <hip/hip_bf16.h>
#include <stdint.h>

namespace {

constexpr int T_LEN = 2048;
constexpr int NROWS = 192;       // 3*64 rows per head
constexpr int QBLK  = 128;       // t-columns per block
constexpr int NBH   = 32;        // 2 batches * 16 heads
constexpr int KT_STRIDE = 72;    // padded row stride (bf16 elems) — R1/R3-validated
constexpr int TILE_ELEMS = 64 * KT_STRIDE;   // 4608 elems = 9216 B per 64-tile
constexpr int TILE_BYTES = TILE_ELEMS * 2;   // 9216 B

typedef float f32x4 __attribute__((ext_vector_type(4)));
typedef short bf16x8 __attribute__((ext_vector_type(8)));
typedef short bf16x4 __attribute__((ext_vector_type(4)));

__device__ __forceinline__ unsigned short f2bf(float f) {
  union { float f; unsigned u; } v; v.f = f;
  unsigned r = v.u + 0x7fffu + ((v.u >> 16) & 1u);   // RNE
  return (unsigned short)(r >> 16);
}
__device__ __forceinline__ unsigned pack2(float a, float b) {
  return (unsigned)f2bf(a) | ((unsigned)f2bf(b) << 16);
}
__device__ __forceinline__ float fast_exp2(float x) {
#if __has_builtin(__builtin_amdgcn_exp2f)
  return __builtin_amdgcn_exp2f(x);
#else
  return exp2f(x);
#endif
}
__device__ __forceinline__ f32x4 mfma_16x16x16_bf16(bf16x4 a, bf16x4 b, f32x4 c) {
#if __has_builtin(__builtin_amdgcn_mfma_f32_16x16x16bf16_1k)
  return __builtin_amdgcn_mfma_f32_16x16x16bf16_1k(a, b, c, 0, 0, 0);
#else
  asm("v_mfma_f32_16x16x16_bf16 %0, %1, %2, %0" : "+v"(c) : "v"(a), "v"(b));
  return c;
#endif
}
// Async global->LDS DMA, 16B per lane: LDS dest = wave-uniform base + lane*16.
__device__ __forceinline__ void gload_lds16(const void* g, void* l) {
  __builtin_amdgcn_global_load_lds(
      (const __attribute__((address_space(1))) unsigned int*)g,
      (__attribute__((address_space(3))) unsigned int*)l, 16, 0, 0);
}

} // namespace

// Normalize mask to uint8 (fallback path). Stride detect via guaranteed-true mask[0][1].
__global__ void nm_kernel(const unsigned char* __restrict__ raw,
                          unsigned char* __restrict__ outm, int n) {
  int stride = (raw[1] != 0) ? 1 : ((raw[4] != 0) ? 4 : 8);
  int i = blockIdx.x * blockDim.x + threadIdx.x;
  if (i < n) outm[i] = (raw[(size_t)i * stride] != 0) ? 1 : 0;
}

// ---------------- merged prepass (R12-validated numerics): ONE launch --------------
// grid (32, NBH, 4), 256 thr.
// z==0: Q -> [bh][t][64] linear, scaled 0.125*log2(e), masked-t rows zeroed.
// z==1: K -> [bh][sb][64][72] tiles.
// z>=2: V -> [bh][sb][64][72] tiles; z==2,bh==0,bx<24 also emit bias table.
__global__ __launch_bounds__(256) void prep12_kernel(const float* __restrict__ qkv,
                                                     const unsigned char* __restrict__ mraw,
                                                     short* __restrict__ qtg,
                                                     short* __restrict__ ktg,
                                                     short* __restrict__ vtg,
                                                     float* __restrict__ bias,
                                                     int mask_elems) {
  const int z  = blockIdx.z;
  const int bh = blockIdx.y;
  const int bx = blockIdx.x;
  const int t  = threadIdx.x;

  if (z >= 2) {
    int cid = ((bh * 64) + (z - 2) * 32 + bx) * 256 + t;
    int bh2 = cid >> 14;
    int rem = cid & 16383;
    int c = rem >> 8;
    int cg = rem & 255;
    int grp = cg >> 3, jin = cg & 7;
    const float* src = qkv + (size_t)bh2 * NROWS * T_LEN + (size_t)(128 + c) * T_LEN + cg * 8;
    float4 a = *(const float4*)src;
    float4 b = *(const float4*)(src + 4);
    bf16x4 o0, o1;
    o0[0] = (short)f2bf(a.x); o0[1] = (short)f2bf(a.y);
    o0[2] = (short)f2bf(a.z); o0[3] = (short)f2bf(a.w);
    o1[0] = (short)f2bf(b.x); o1[1] = (short)f2bf(b.y);
    o1[2] = (short)f2bf(b.z); o1[3] = (short)f2bf(b.w);
    short* d = vtg + (size_t)(bh2 * 32 + grp) * TILE_ELEMS + c * KT_STRIDE + jin * 8;
    *(bf16x4*)d = o0;
    *(bf16x4*)(d + 4) = o1;
    if (z == 2 && bh == 0 && bx < 24) {
      int i = bx * 256 + t;
      int stride = (mraw[1] != 0) ? 1 : ((mraw[4] != 0) ? 4 : 8);
      if (i < mask_elems) bias[i] = (mraw[(size_t)i * stride] != 0) ? 0.0f : -1.0e30f;
      else if (i < mask_elems + T_LEN) bias[i] = 0.0f;
    }
    return;
  }

  __shared__ float tile[64][65];
  const int s0 = bx * 64;
  const float* src = qkv + (size_t)bh * NROWS * T_LEN + (size_t)z * 64 * T_LEN;
  const int c = t >> 2;
  #pragma unroll
  for (int p = 0; p < 4; ++p) {
    int col = (t & 3) * 4 + p * 16;
    float4 v = *(const float4*)&src[(size_t)c * T_LEN + s0 + col];
    tile[c][col] = v.x; tile[c][col + 1] = v.y;
    tile[c][col + 2] = v.z; tile[c][col + 3] = v.w;
  }
  __syncthreads();
  const int s = t & 63;
  float scale;
  if (z) {
    scale = 1.0f;
  } else {
    const int mstride = (mraw[1] != 0) ? 1 : ((mraw[4] != 0) ? 4 : 8);
    const int nb = bh >> 4;
    const bool live = mraw[((size_t)nb * T_LEN + s0 + s) * mstride] != 0;
    scale = live ? 0.18033688011112042f : 0.0f;   // 0.125*log2(e), 0 for masked t
  }
  #pragma unroll
  for (int p = 0; p < 2; ++p) {
    int jc = (t >> 6) * 2 + p;
    bf16x4 o0, o1;
    #pragma unroll
    for (int i = 0; i < 4; ++i) {
      o0[i] = (short)f2bf(tile[jc * 8 + i][s] * scale);
      o1[i] = (short)f2bf(tile[jc * 8 + 4 + i][s] * scale);
    }
    short* d = z
      ? (ktg + (size_t)(bh * 32 + bx) * TILE_ELEMS + s * KT_STRIDE + jc * 8)
      : (qtg + (size_t)bh * T_LEN * 64 + (size_t)(s0 + s) * 64 + jc * 8);
    *(bf16x4*)d = o0;
    *(bf16x4*)(d + 4) = o1;
  }
}

// ------ attn13: 512 thr, 8 waves, QBLK=128. sgrp=wv&3 owns st; tgrp=wv>>2 owns
// FOUR t-windows (t0 + tgrp*64 + j*16). K/V fragments read once per wave serve
// 4 t-windows (LDS reads per CU halve vs R11). Bias: single load + fma(b4,live,S).
// launch_bounds(512,4): VGPR cap 128 (no R12-style spill), 2 blocks/CU.

__global__ __launch_bounds__(512, 4) void attn13_kernel(const short* __restrict__ qtg,
                                                        const short* __restrict__ ktg,
                                                        const short* __restrict__ vtg,
                                                        const float* __restrict__ bias,
                                                        float* __restrict__ out) {
  __shared__ __align__(16) short smem[4 * TILE_ELEMS];   // K0|K1|V0|V1 (36864 B)

  const int tid  = threadIdx.x;
  const int lane = tid & 63;
  const int wv   = tid >> 6;    // 0..7
  const int sgrp = wv & 3;      // owns st = sgrp
  const int tgrp = wv >> 2;     // 0..1 — owns t-windows t0+tgrp*64+{0,16,32,48}
  const int l15  = lane & 15;
  const int g    = lane >> 4;

  int id = blockIdx.x;
  id = (id & 7) * 64 + (id >> 3);    // bijective XCD swizzle over 512 blocks
  const int bh = id >> 4;
  const int t0 = (id & 15) * QBLK;
  const int nb = bh >> 4;

  // four t-columns per wave
  int tarr[4];
  #pragma unroll
  for (int j = 0; j < 4; ++j) tarr[j] = t0 + tgrp * 64 + j * 16 + l15;

  // Q fragments (masked-t rows pre-zeroed) + live flags
  const short* Qbase = qtg + (size_t)bh * T_LEN * 64;
  bf16x8 qf0[4], qf1[4];
  float live[4];
  #pragma unroll
  for (int j = 0; j < 4; ++j) {
    qf0[j] = *(const bf16x8*)(Qbase + (size_t)tarr[j] * 64 + g * 8);
    qf1[j] = *(const bf16x8*)(Qbase + (size_t)tarr[j] * 64 + 32 + g * 8);
    live[j] = (bias[(size_t)nb * T_LEN + tarr[j]] == 0.0f) ? 1.0f : 0.0f;
  }
  const float* __restrict__ brow = bias + (size_t)nb * T_LEN;

  const char* __restrict__ kt0 = (const char*)(ktg + (size_t)bh * 32 * TILE_ELEMS);
  const char* __restrict__ vt0 = (const char*)(vtg + (size_t)bh * 32 * TILE_ELEMS);
  char* KtL = (char*)smem;
  char* VsL = (char*)(smem + 2 * TILE_ELEMS);

  // prologue: DMA tile 0 -> buf 0 (9 K chunks + 9 V chunks of 1024 B, R11 mapping)
  gload_lds16(kt0 + wv * 1024 + lane * 16, KtL + wv * 1024);
  gload_lds16(vt0 + wv * 1024 + lane * 16, VsL + wv * 1024);
  if (wv == 0) gload_lds16(kt0 + 8192 + lane * 16, KtL + 8192);
  if (wv == 1) gload_lds16(vt0 + 8192 + lane * 16, VsL + 8192);
  __syncthreads();                     // drains DMA (vmcnt) + joins waves

  f32x4 acc[4][4];                     // [j][cb]
  #pragma unroll
  for (int j = 0; j < 4; ++j)
    #pragma unroll
    for (int cb = 0; cb < 4; ++cb) acc[j][cb] = (f32x4){0.f, 0.f, 0.f, 0.f};
  float lp[4] = {0.f, 0.f, 0.f, 0.f};

  const int koff = (sgrp * 16 + l15) * KT_STRIDE;
  const int boff = sgrp * 16 + g * 4;

  int cur = 0;
  for (int sb = 0; sb < T_LEN / 64; ++sb) {
    if (sb + 1 < T_LEN / 64) {         // T14: next tile's DMA flies under compute
      const char* ks = kt0 + (size_t)(sb + 1) * TILE_BYTES;
      const char* vs = vt0 + (size_t)(sb + 1) * TILE_BYTES;
      char* Ktn = KtL + (cur ^ 1) * TILE_BYTES;
      char* Vsn = VsL + (cur ^ 1) * TILE_BYTES;
      gload_lds16(ks + wv * 1024 + lane * 16, Ktn + wv * 1024);
      gload_lds16(vs + wv * 1024 + lane * 16, Vsn + wv * 1024);
      if (wv == 0) gload_lds16(ks + 8192 + lane * 16, Ktn + 8192);
      if (wv == 1) gload_lds16(vs + 8192 + lane * 16, Vsn + 8192);
    }

    const short* Ktc = smem + cur * TILE_ELEMS;
    const short* Vsc = smem + (2 + cur) * TILE_ELEMS;

    // K fragment read ONCE per wave, shared by 4 t-windows
    bf16x8 kf0 = *(const bf16x8*)&Ktc[koff + g * 8];
    bf16x8 kf1 = *(const bf16x8*)&Ktc[koff + 32 + g * 8];
    // bias for this wave's s-rows, loaded ONCE (applied per-tw via live flag)
    const f32x4 b4 = *(const f32x4*)&brow[sb * 64 + boff];

    union { bf16x4 v; __hip_bfloat162 h[2]; } pf[4];
    #pragma unroll
    for (int j = 0; j < 4; ++j) {
      f32x4 S = (f32x4){0.f, 0.f, 0.f, 0.f};
      S = __builtin_amdgcn_mfma_f32_16x16x32_bf16(kf0, qf0[j], S, 0, 0, 0);
      S = __builtin_amdgcn_mfma_f32_16x16x32_bf16(kf1, qf1[j], S, 0, 0, 0);
      // p = exp2(S + b4*live): masked t -> S=0, b4*0=0 -> p=1 (uniform);
      // live t masked s -> S-1e30 -> p=0.
      float p0 = fast_exp2(__builtin_fmaf(b4[0], live[j], S[0]));
      float p1 = fast_exp2(__builtin_fmaf(b4[1], live[j], S[1]));
      float p2 = fast_exp2(__builtin_fmaf(b4[2], live[j], S[2]));
      float p3 = fast_exp2(__builtin_fmaf(b4[3], live[j], S[3]));
      lp[j] += (p0 + p1) + (p2 + p3);
      pf[j].h[0] = __float22bfloat162_rn(float2{p0, p1});
      pf[j].h[1] = __float22bfloat162_rn(float2{p2, p3});
    }

    // V fragment read ONCE per cb, shared by 4 t-windows
    #pragma unroll
    for (int cb = 0; cb < 4; ++cb) {
      bf16x4 vf = *(const bf16x4*)&Vsc[(cb * 16 + l15) * KT_STRIDE + sgrp * 16 + g * 4];
      #pragma unroll
      for (int j = 0; j < 4; ++j)
        acc[j][cb] = mfma_16x16x16_bf16(vf, pf[j].v, acc[j][cb]);
    }

    __syncthreads();                   // reads of buf[cur] done; DMA drained
    cur ^= 1;
  }

  // ---- 4-partial combine over sgrp: 3 pair-rounds. Slot[tgrp]: 64 lanes x 72 f
  // (64 acc + 4 l + pad) = 18432 B; 2 slots = 36864 B = smem exactly.
  float* scr = (float*)smem;
  const int lb = tgrp * 4608 + lane * 72;
  #define DUMP_ROW  { float* b_ = scr + lb;                                    \
      _Pragma("unroll") for (int j = 0; j < 4; ++j) {                          \
        _Pragma("unroll") for (int cb = 0; cb < 4; ++cb)                       \
          *(f32x4*)&b_[j * 16 + cb * 4] = acc[j][cb];                          \
        b_[64 + j] = lp[j]; } }
  #define ADD_ROW   { const float* b_ = scr + lb;                              \
      _Pragma("unroll") for (int j = 0; j < 4; ++j) {                          \
        _Pragma("unroll") for (int cb = 0; cb < 4; ++cb)                       \
          acc[j][cb] += *(const f32x4*)&b_[j * 16 + cb * 4];                   \
        lp[j] += b_[64 + j]; } }
  if (sgrp == 3) DUMP_ROW
  __syncthreads();
  if (sgrp == 1) ADD_ROW           // 1 += 3
  __syncthreads();
  if (sgrp == 2) DUMP_ROW
  __syncthreads();
  if (sgrp == 0) ADD_ROW           // 0 += 2
  __syncthreads();
  if (sgrp == 1) DUMP_ROW          // holds 1+3
  __syncthreads();
  if (sgrp == 0) {
    ADD_ROW                        // 0+2+1+3
    const size_t out_base = (size_t)bh * 64 * T_LEN;
    #pragma unroll
    for (int j = 0; j < 4; ++j) {
      float l = lp[j];
      l += __shfl_xor(l, 16, 64);
      l += __shfl_xor(l, 32, 64);
      const float il = 1.0f / l;
      #pragma unroll
      for (int cb = 0; cb < 4; ++cb) {
        #pragma unroll
        for (int r = 0; r < 4; ++r) {
          int c = cb * 16 + g * 4 + r;
          out[out_base + (size_t)c * T_LEN + tarr[j]] = acc[j][cb][r] * il;
        }
      }
    }
  }
  #undef DUMP_ROW
  #undef ADD_ROW
}

// ---------------- fallback path (round-1 kernel, used if ws too small) ------------

__global__ __launch_bounds__(256) void attn_fb_kernel(const float* __restrict__ qkv,
                                                      const unsigned char* __restrict__ maskn,
                                                      float* __restrict__ out) {
  __shared__ __align__(16) short Kt[64 * KT_STRIDE];
  __shared__ __align__(16) short Vs[64 * KT_STRIDE];
  __shared__ __align__(16) unsigned char Ms[T_LEN];

  const int tid  = threadIdx.x;
  const int lane = tid & 63;
  const int wv   = tid >> 6;
  const int l15  = lane & 15;
  const int g    = lane >> 4;

  const int bh = blockIdx.y;
  const int nb = bh >> 4;
  const int t0 = blockIdx.x * 64;

  const float* __restrict__ Qg = qkv + (size_t)bh * NROWS * T_LEN;
  const float* __restrict__ Kg = Qg + (size_t)64 * T_LEN;
  const float* __restrict__ Vg = Qg + (size_t)128 * T_LEN;

  {
    const uint2* src = (const uint2*)(maskn + (size_t)nb * T_LEN);
    ((uint2*)Ms)[tid] = src[tid];
  }
  {
    const int c2 = (tid >> 6) * 2;
    const int s  = tid & 63;
    #pragma unroll
    for (int p = 0; p < 8; ++p) {
      int c = p * 8 + c2;
      float f0 = Qg[(size_t)c * T_LEN + t0 + s] * 0.125f;
      float f1 = Qg[(size_t)(c + 1) * T_LEN + t0 + s] * 0.125f;
      *(unsigned*)&Kt[s * KT_STRIDE + c] = pack2(f0, f1);
    }
  }
  __syncthreads();

  bf16x8 qf0 = *(const bf16x8*)&Kt[(wv * 16 + l15) * KT_STRIDE + g * 8];
  bf16x8 qf1 = *(const bf16x8*)&Kt[(wv * 16 + l15) * KT_STRIDE + 32 + g * 8];
  const int t_lane = t0 + wv * 16 + l15;
  const bool invt = (Ms[t_lane] == 0);

  f32x4 acc[4];
  #pragma unroll
  for (int i = 0; i < 4; ++i) acc[i] = (f32x4){0.f, 0.f, 0.f, 0.f};
  float m_run = -3.0e38f;
  float l_run = 0.0f;

  for (int sb = 0; sb < T_LEN / 64; ++sb) {
    const int s0 = sb * 64;
    __syncthreads();
    {
      const int c2 = (tid >> 6) * 2;
      const int s  = tid & 63;
      #pragma unroll
      for (int p = 0; p < 8; ++p) {
        int c = p * 8 + c2;
        float f0 = Kg[(size_t)c * T_LEN + s0 + s];
        float f1 = Kg[(size_t)(c + 1) * T_LEN + s0 + s];
        *(unsigned*)&Kt[s * KT_STRIDE + c] = pack2(f0, f1);
      }
    }
    {
      const int cv = (tid >> 5);
      const int s2 = tid & 31;
      #pragma unroll
      for (int p = 0; p < 8; ++p) {
        int c = p * 8 + cv;
        float2 f = *(const float2*)&Vg[(size_t)c * T_LEN + s0 + 2 * s2];
        *(unsigned*)&Vs[c * KT_STRIDE + 2 * s2] = pack2(f.x, f.y);
      }
    }
    __syncthreads();

    #pragma unroll
    for (int st = 0; st < 4; ++st) {
      const int srow = st * 16 + l15;
      bf16x8 kf0 = *(const bf16x8*)&Kt[srow * KT_STRIDE + g * 8];
      bf16x8 kf1 = *(const bf16x8*)&Kt[srow * KT_STRIDE + 32 + g * 8];
      f32x4 S = (f32x4){0.f, 0.f, 0.f, 0.f};
      S = __builtin_amdgcn_mfma_f32_16x16x32_bf16(kf0, qf0, S, 0, 0, 0);
      S = __builtin_amdgcn_mfma_f32_16x16x32_bf16(kf1, qf1, S, 0, 0, 0);

      const unsigned m4 = *(const unsigned*)&Ms[s0 + st * 16 + g * 4];
      float vals[4];
      #pragma unroll
      for (int r = 0; r < 4; ++r) {
        float x = ((m4 >> (8 * r)) & 0xffu) ? S[r] : -1.0e30f;
        vals[r] = invt ? 0.0f : x;
      }
      float pm = fmaxf(fmaxf(vals[0], vals[1]), fmaxf(vals[2], vals[3]));
      pm = fmaxf(pm, __shfl_xor(pm, 16, 64));
      pm = fmaxf(pm, __shfl_xor(pm, 32, 64));
      const float newm = fmaxf(m_run, pm);
      const float alpha = fast_exp2((m_run - newm) * 1.44269504f);
      float p0 = fast_exp2((vals[0] - newm) * 1.44269504f);
      float p1 = fast_exp2((vals[1] - newm) * 1.44269504f);
      float p2 = fast_exp2((vals[2] - newm) * 1.44269504f);
      float p3 = fast_exp2((vals[3] - newm) * 1.44269504f);
      float ps = (p0 + p1) + (p2 + p3);
      ps += __shfl_xor(ps, 16, 64);
      ps += __shfl_xor(ps, 32, 64);
      l_run = l_run * alpha + ps;
      m_run = newm;
      if (__any(alpha < 1.0f)) {
        #pragma unroll
        for (int cb = 0; cb < 4; ++cb)
          #pragma unroll
          for (int r = 0; r < 4; ++r) acc[cb][r] *= alpha;
      }
      bf16x4 pf;
      pf[0] = (short)f2bf(p0); pf[1] = (short)f2bf(p1);
      pf[2] = (short)f2bf(p2); pf[3] = (short)f2bf(p3);
      #pragma unroll
      for (int cb = 0; cb < 4; ++cb) {
        bf16x4 vf = *(const bf16x4*)&Vs[(cb * 16 + l15) * KT_STRIDE + st * 16 + g * 4];
        acc[cb] = mfma_16x16x16_bf16(vf, pf, acc[cb]);
      }
    }
  }

  const float il = 1.0f / l_run;
  const size_t out_base = (size_t)bh * 64 * T_LEN;
  #pragma unroll
  for (int cb = 0; cb < 4; ++cb) {
    #pragma unroll
    for (int r = 0; r < 4; ++r) {
      int c = cb * 16 + g * 4 + r;
      out[out_base + (size_t)c * T_LEN + t_lane] = acc[cb][r] * il;
    }
  }
}

// ---------------- launch ----------------

extern "C" void kernel_launch(void* const* d_in, const int* in_sizes, int n_in,
                              void* d_out, int out_size, void* d_ws, size_t ws_size,
                              hipStream_t stream) {
  (void)n_in; (void)out_size;
  const float* qkv = (const float*)d_in[0];
  const unsigned char* mraw = (const unsigned char*)d_in[1];
  float* out = (float*)d_out;
  const int mask_elems = in_sizes[1];   // 2*2048

  // ws layout: qtg(8 MB) | ktg tiles(9 MB) | vtg tiles(9 MB) | bias((mask_elems+2048)*4)
  const size_t QSZ = (size_t)NBH * T_LEN * 64 * sizeof(short);          // 8388608
  const size_t TSZ = (size_t)NBH * 32 * TILE_ELEMS * sizeof(short);     // 9437184
  const size_t BSZ = (size_t)(mask_elems + T_LEN) * sizeof(float);
  const size_t need = QSZ + 2 * TSZ + BSZ;
  if (ws_size >= need) {
    short* qtg = (short*)d_ws;
    short* ktg = (short*)((char*)d_ws + QSZ);
    short* vtg = (short*)((char*)d_ws + QSZ + TSZ);
    float* bias = (float*)((char*)d_ws + QSZ + 2 * TSZ);
    prep12_kernel<<<dim3(32, NBH, 4), 256, 0, stream>>>(qkv, mraw, qtg, ktg, vtg,
                                                        bias, mask_elems);
    attn13_kernel<<<dim3(NBH * 16), 512, 0, stream>>>(qtg, ktg, vtg, bias, out);
  } else {
    unsigned char* maskn = (unsigned char*)d_ws;
    nm_kernel<<<(mask_elems + 255) / 256, 256, 0, stream>>>(mraw, maskn, mask_elems);
    attn_fb_kernel<<<dim3(T_LEN / 64, NBH), 256, 0, stream>>>(qkv, maskn, out);
  }
}

// Round 14
// 84.980 us; speedup vs baseline: 2.4909x; 1.5352x over previous
//
#include <hip/hip_runtime.h>
#include <hip/hip_bf16.h>
#include <stdint.h>

namespace {

constexpr int T_LEN = 2048;
constexpr int NROWS = 192;       // 3*64 rows per head
constexpr int QBLK  = 64;
constexpr int NBH   = 32;        // 2 batches * 16 heads
constexpr int KT_STRIDE = 72;    // padded row stride (bf16 elems) — R1/R3-validated
constexpr int TILE_ELEMS = 64 * KT_STRIDE;   // 4608 elems = 9216 B per 64-tile
constexpr int TILE_BYTES = TILE_ELEMS * 2;   // 9216 B

typedef float f32x4 __attribute__((ext_vector_type(4)));
typedef short bf16x8 __attribute__((ext_vector_type(8)));
typedef short bf16x4 __attribute__((ext_vector_type(4)));

__device__ __forceinline__ unsigned short f2bf(float f) {
  union { float f; unsigned u; } v; v.f = f;
  unsigned r = v.u + 0x7fffu + ((v.u >> 16) & 1u);   // RNE
  return (unsigned short)(r >> 16);
}
__device__ __forceinline__ unsigned pack2(float a, float b) {
  return (unsigned)f2bf(a) | ((unsigned)f2bf(b) << 16);
}
__device__ __forceinline__ float fast_exp2(float x) {
#if __has_builtin(__builtin_amdgcn_exp2f)
  return __builtin_amdgcn_exp2f(x);
#else
  return exp2f(x);
#endif
}
__device__ __forceinline__ f32x4 mfma_16x16x16_bf16(bf16x4 a, bf16x4 b, f32x4 c) {
#if __has_builtin(__builtin_amdgcn_mfma_f32_16x16x16bf16_1k)
  return __builtin_amdgcn_mfma_f32_16x16x16bf16_1k(a, b, c, 0, 0, 0);
#else
  asm("v_mfma_f32_16x16x16_bf16 %0, %1, %2, %0" : "+v"(c) : "v"(a), "v"(b));
  return c;
#endif
}
// Async global->LDS DMA, 16B per lane: LDS dest = wave-uniform base + lane*16.
__device__ __forceinline__ void gload_lds16(const void* g, void* l) {
  __builtin_amdgcn_global_load_lds(
      (const __attribute__((address_space(1))) unsigned int*)g,
      (__attribute__((address_space(3))) unsigned int*)l, 16, 0, 0);
}

} // namespace

// Normalize mask to uint8 (fallback path). Stride detect via guaranteed-true mask[0][1].
__global__ void nm_kernel(const unsigned char* __restrict__ raw,
                          unsigned char* __restrict__ outm, int n) {
  int stride = (raw[1] != 0) ? 1 : ((raw[4] != 0) ? 4 : 8);
  int i = blockIdx.x * blockDim.x + threadIdx.x;
  if (i < n) outm[i] = (raw[(size_t)i * stride] != 0) ? 1 : 0;
}

// ---------------- merged prepass (R12/R13-validated numerics): ONE launch ----------
// grid (32, NBH, 4), 256 thr.
// z==0: Q -> [bh][t][64] linear, scaled 0.125*log2(e), masked-t rows zeroed.
// z==1: K -> [bh][sb][64][72] tiles.
// z>=2: V -> [bh][sb][64][72] tiles; z==2,bh==0,bx<24 also emit bias table
//        (mask_elems entries {0,-1e30} + T_LEN zero row).
__global__ __launch_bounds__(256) void prep12_kernel(const float* __restrict__ qkv,
                                                     const unsigned char* __restrict__ mraw,
                                                     short* __restrict__ qtg,
                                                     short* __restrict__ ktg,
                                                     short* __restrict__ vtg,
                                                     float* __restrict__ bias,
                                                     int mask_elems) {
  const int z  = blockIdx.z;
  const int bh = blockIdx.y;
  const int bx = blockIdx.x;
  const int t  = threadIdx.x;

  if (z >= 2) {
    int cid = ((bh * 64) + (z - 2) * 32 + bx) * 256 + t;
    int bh2 = cid >> 14;
    int rem = cid & 16383;
    int c = rem >> 8;
    int cg = rem & 255;
    int grp = cg >> 3, jin = cg & 7;
    const float* src = qkv + (size_t)bh2 * NROWS * T_LEN + (size_t)(128 + c) * T_LEN + cg * 8;
    float4 a = *(const float4*)src;
    float4 b = *(const float4*)(src + 4);
    bf16x4 o0, o1;
    o0[0] = (short)f2bf(a.x); o0[1] = (short)f2bf(a.y);
    o0[2] = (short)f2bf(a.z); o0[3] = (short)f2bf(a.w);
    o1[0] = (short)f2bf(b.x); o1[1] = (short)f2bf(b.y);
    o1[2] = (short)f2bf(b.z); o1[3] = (short)f2bf(b.w);
    short* d = vtg + (size_t)(bh2 * 32 + grp) * TILE_ELEMS + c * KT_STRIDE + jin * 8;
    *(bf16x4*)d = o0;
    *(bf16x4*)(d + 4) = o1;
    if (z == 2 && bh == 0 && bx < 24) {
      int i = bx * 256 + t;
      int stride = (mraw[1] != 0) ? 1 : ((mraw[4] != 0) ? 4 : 8);
      if (i < mask_elems) bias[i] = (mraw[(size_t)i * stride] != 0) ? 0.0f : -1.0e30f;
      else if (i < mask_elems + T_LEN) bias[i] = 0.0f;
    }
    return;
  }

  __shared__ float tile[64][65];
  const int s0 = bx * 64;
  const float* src = qkv + (size_t)bh * NROWS * T_LEN + (size_t)z * 64 * T_LEN;
  const int c = t >> 2;
  #pragma unroll
  for (int p = 0; p < 4; ++p) {
    int col = (t & 3) * 4 + p * 16;
    float4 v = *(const float4*)&src[(size_t)c * T_LEN + s0 + col];
    tile[c][col] = v.x; tile[c][col + 1] = v.y;
    tile[c][col + 2] = v.z; tile[c][col + 3] = v.w;
  }
  __syncthreads();
  const int s = t & 63;
  float scale;
  if (z) {
    scale = 1.0f;
  } else {
    const int mstride = (mraw[1] != 0) ? 1 : ((mraw[4] != 0) ? 4 : 8);
    const int nb = bh >> 4;
    const bool live = mraw[((size_t)nb * T_LEN + s0 + s) * mstride] != 0;
    scale = live ? 0.18033688011112042f : 0.0f;   // 0.125*log2(e), 0 for masked t
  }
  #pragma unroll
  for (int p = 0; p < 2; ++p) {
    int jc = (t >> 6) * 2 + p;
    bf16x4 o0, o1;
    #pragma unroll
    for (int i = 0; i < 4; ++i) {
      o0[i] = (short)f2bf(tile[jc * 8 + i][s] * scale);
      o1[i] = (short)f2bf(tile[jc * 8 + 4 + i][s] * scale);
    }
    short* d = z
      ? (ktg + (size_t)(bh * 32 + bx) * TILE_ELEMS + s * KT_STRIDE + jc * 8)
      : (qtg + (size_t)bh * T_LEN * 64 + (size_t)(s0 + s) * 64 + jc * 8);
    *(bf16x4*)d = o0;
    *(bf16x4*)(d + 4) = o1;
  }
}

// ------ attn11 (R11-verbatim, 73.4 µs measured): 8 waves, sgrp=wv&3 owns st,
// tgrp=wv>>2 owns 2 t-windows. DMA staging, bias masking, 2-round combine tree.

__global__ __launch_bounds__(512, 4) void attn11_kernel(const short* __restrict__ qtg,
                                                        const short* __restrict__ ktg,
                                                        const short* __restrict__ vtg,
                                                        const float* __restrict__ bias,
                                                        int mask_elems,
                                                        float* __restrict__ out) {
  __shared__ __align__(16) short smem[4 * TILE_ELEMS];   // K0|K1|V0|V1 (36864 B)

  const int tid  = threadIdx.x;
  const int lane = tid & 63;
  const int wv   = tid >> 6;    // 0..7
  const int sgrp = wv & 3;      // owns st = sgrp
  const int tgrp = wv >> 2;     // owns tw = {2*tgrp, 2*tgrp+1}
  const int l15  = lane & 15;
  const int g    = lane >> 4;

  int id = blockIdx.x;
  id = (id & 7) * 128 + (id >> 3);   // bijective XCD swizzle (bit-rotation)
  const int bh = id >> 5;
  const int t0 = (id & 31) * QBLK;
  const int nb = bh >> 4;

  // two t-columns per wave
  const int tA = t0 + (tgrp * 2) * 16 + l15;
  const int tB = tA + 16;

  // Q fragments (masked-t rows pre-zeroed by prep12)
  const short* Qbase = qtg + (size_t)bh * T_LEN * 64;
  const bf16x8 qfA0 = *(const bf16x8*)(Qbase + (size_t)tA * 64 + g * 8);
  const bf16x8 qfA1 = *(const bf16x8*)(Qbase + (size_t)tA * 64 + 32 + g * 8);
  const bf16x8 qfB0 = *(const bf16x8*)(Qbase + (size_t)tB * 64 + g * 8);
  const bf16x8 qfB1 = *(const bf16x8*)(Qbase + (size_t)tB * 64 + 32 + g * 8);

  // per-tw bias row: live t -> batch row; masked t -> zero row (uniform softmax)
  const float btA = bias[(size_t)nb * T_LEN + tA];
  const float btB = bias[(size_t)nb * T_LEN + tB];
  const float* __restrict__ browA = bias + ((btA != 0.0f) ? (size_t)mask_elems
                                                          : (size_t)nb * T_LEN);
  const float* __restrict__ browB = bias + ((btB != 0.0f) ? (size_t)mask_elems
                                                          : (size_t)nb * T_LEN);

  const char* __restrict__ kt0 = (const char*)(ktg + (size_t)bh * 32 * TILE_ELEMS);
  const char* __restrict__ vt0 = (const char*)(vtg + (size_t)bh * 32 * TILE_ELEMS);
  char* KtL = (char*)smem;                               // K double-buffer base
  char* VsL = (char*)(smem + 2 * TILE_ELEMS);            // V double-buffer base

  // prologue: DMA tile 0 -> buf 0 (9216 B each = 8 wave-chunks + 1 extra)
  gload_lds16(kt0 + wv * 1024 + lane * 16, KtL + wv * 1024);
  gload_lds16(vt0 + wv * 1024 + lane * 16, VsL + wv * 1024);
  if (wv == 0) gload_lds16(kt0 + 8192 + lane * 16, KtL + 8192);
  if (wv == 1) gload_lds16(vt0 + 8192 + lane * 16, VsL + 8192);
  __syncthreads();                     // drains DMA (vmcnt) + joins waves

  f32x4 accA[4], accB[4];
  #pragma unroll
  for (int i = 0; i < 4; ++i) { accA[i] = (f32x4){0.f,0.f,0.f,0.f}; accB[i] = accA[i]; }
  float lA = 0.0f, lB = 0.0f;

  const int koff = (sgrp * 16 + l15) * KT_STRIDE;   // this wave's K row base
  const int boff = sgrp * 16 + g * 4;               // bias offset within 64-s tile

  int cur = 0;
  for (int sb = 0; sb < T_LEN / 64; ++sb) {
    // issue next tile's DMA first: flies under this tile's compute (T14)
    if (sb + 1 < T_LEN / 64) {
      const char* ks = kt0 + (size_t)(sb + 1) * TILE_BYTES;
      const char* vs = vt0 + (size_t)(sb + 1) * TILE_BYTES;
      char* Ktn = KtL + (cur ^ 1) * TILE_BYTES;
      char* Vsn = VsL + (cur ^ 1) * TILE_BYTES;
      gload_lds16(ks + wv * 1024 + lane * 16, Ktn + wv * 1024);
      gload_lds16(vs + wv * 1024 + lane * 16, Vsn + wv * 1024);
      if (wv == 0) gload_lds16(ks + 8192 + lane * 16, Ktn + 8192);
      if (wv == 1) gload_lds16(vs + 8192 + lane * 16, Vsn + 8192);
    }

    const short* Ktc = smem + cur * TILE_ELEMS;
    const short* Vsc = smem + (2 + cur) * TILE_ELEMS;

    // K fragment read ONCE per wave, shared by both t-windows
    bf16x8 kf0 = *(const bf16x8*)&Ktc[koff + g * 8];
    bf16x8 kf1 = *(const bf16x8*)&Ktc[koff + 32 + g * 8];

    f32x4 SA = (f32x4){0.f, 0.f, 0.f, 0.f};
    SA = __builtin_amdgcn_mfma_f32_16x16x32_bf16(kf0, qfA0, SA, 0, 0, 0);
    SA = __builtin_amdgcn_mfma_f32_16x16x32_bf16(kf1, qfA1, SA, 0, 0, 0);
    f32x4 SB = (f32x4){0.f, 0.f, 0.f, 0.f};
    SB = __builtin_amdgcn_mfma_f32_16x16x32_bf16(kf0, qfB0, SB, 0, 0, 0);
    SB = __builtin_amdgcn_mfma_f32_16x16x32_bf16(kf1, qfB1, SB, 0, 0, 0);

    // lane holds S[s = sb*64+sgrp*16+g*4+r][t], log2 domain; bias = 0 / -1e30
    const f32x4 b4A = *(const f32x4*)&browA[sb * 64 + boff];
    const f32x4 b4B = *(const f32x4*)&browB[sb * 64 + boff];
    float pA0 = fast_exp2(SA[0] + b4A[0]);
    float pA1 = fast_exp2(SA[1] + b4A[1]);
    float pA2 = fast_exp2(SA[2] + b4A[2]);
    float pA3 = fast_exp2(SA[3] + b4A[3]);
    lA += (pA0 + pA1) + (pA2 + pA3);
    float pB0 = fast_exp2(SB[0] + b4B[0]);
    float pB1 = fast_exp2(SB[1] + b4B[1]);
    float pB2 = fast_exp2(SB[2] + b4B[2]);
    float pB3 = fast_exp2(SB[3] + b4B[3]);
    lB += (pB0 + pB1) + (pB2 + pB3);

    union { bf16x4 v; __hip_bfloat162 h[2]; } pfA, pfB;
    pfA.h[0] = __float22bfloat162_rn(float2{pA0, pA1});
    pfA.h[1] = __float22bfloat162_rn(float2{pA2, pA3});
    pfB.h[0] = __float22bfloat162_rn(float2{pB0, pB1});
    pfB.h[1] = __float22bfloat162_rn(float2{pB2, pB3});

    // V fragment read ONCE per cb, shared by both t-windows
    #pragma unroll
    for (int cb = 0; cb < 4; ++cb) {
      bf16x4 vf = *(const bf16x4*)&Vsc[(cb * 16 + l15) * KT_STRIDE + sgrp * 16 + g * 4];
      accA[cb] = mfma_16x16x16_bf16(vf, pfA.v, accA[cb]);
      accB[cb] = mfma_16x16x16_bf16(vf, pfB.v, accB[cb]);
    }

    __syncthreads();                   // reads of buf[cur] done; DMA into buf[cur^1] drained
    cur ^= 1;
  }

  // ---- 4-partial combine over sgrp (two-round tree, R7/R11-validated pattern).
  // Slot: 64 lanes x 36 floats (32 acc + 2 l + pad) = 9216 B; 4 slots fill smem.
  float* scr = (float*)smem;
  {
    const int lb = lane * 36;
    if (sgrp >= 2) {                   // round 1 writers: slots (sgrp-2)*2 + tgrp
      float* base = scr + ((sgrp - 2) * 2 + tgrp) * 2304 + lb;
      #pragma unroll
      for (int cb = 0; cb < 4; ++cb) {
        *(f32x4*)&base[cb * 4] = accA[cb];
        *(f32x4*)&base[16 + cb * 4] = accB[cb];
      }
      base[32] = lA; base[33] = lB;
    }
    __syncthreads();
    if (sgrp < 2) {                    // round 1 readers: slots sgrp*2 + tgrp
      const float* base = scr + (sgrp * 2 + tgrp) * 2304 + lb;
      #pragma unroll
      for (int cb = 0; cb < 4; ++cb) {
        accA[cb] += *(const f32x4*)&base[cb * 4];
        accB[cb] += *(const f32x4*)&base[16 + cb * 4];
      }
      lA += base[32]; lB += base[33];
    }
    __syncthreads();
    if (sgrp == 1) {                   // round 2 writer: slot tgrp
      float* base = scr + tgrp * 2304 + lb;
      #pragma unroll
      for (int cb = 0; cb < 4; ++cb) {
        *(f32x4*)&base[cb * 4] = accA[cb];
        *(f32x4*)&base[16 + cb * 4] = accB[cb];
      }
      base[32] = lA; base[33] = lB;
    }
    __syncthreads();
    if (sgrp == 0) {                   // round 2 reader + epilogue
      const float* base = scr + tgrp * 2304 + lb;
      #pragma unroll
      for (int cb = 0; cb < 4; ++cb) {
        accA[cb] += *(const f32x4*)&base[cb * 4];
        accB[cb] += *(const f32x4*)&base[16 + cb * 4];
      }
      lA += base[32]; lB += base[33];

      lA += __shfl_xor(lA, 16, 64);
      lA += __shfl_xor(lA, 32, 64);
      lB += __shfl_xor(lB, 16, 64);
      lB += __shfl_xor(lB, 32, 64);
      const float ilA = 1.0f / lA;
      const float ilB = 1.0f / lB;
      const size_t out_base = (size_t)bh * 64 * T_LEN;
      #pragma unroll
      for (int cb = 0; cb < 4; ++cb) {
        #pragma unroll
        for (int r = 0; r < 4; ++r) {
          int c = cb * 16 + g * 4 + r;
          out[out_base + (size_t)c * T_LEN + tA] = accA[cb][r] * ilA;
          out[out_base + (size_t)c * T_LEN + tB] = accB[cb][r] * ilB;
        }
      }
    }
  }
}

// ---------------- fallback path (round-1 kernel, used if ws too small) ------------

__global__ __launch_bounds__(256) void attn_fb_kernel(const float* __restrict__ qkv,
                                                      const unsigned char* __restrict__ maskn,
                                                      float* __restrict__ out) {
  __shared__ __align__(16) short Kt[QBLK * KT_STRIDE];
  __shared__ __align__(16) short Vs[64 * KT_STRIDE];
  __shared__ __align__(16) unsigned char Ms[T_LEN];

  const int tid  = threadIdx.x;
  const int lane = tid & 63;
  const int wv   = tid >> 6;
  const int l15  = lane & 15;
  const int g    = lane >> 4;

  const int bh = blockIdx.y;
  const int nb = bh >> 4;
  const int t0 = blockIdx.x * QBLK;

  const float* __restrict__ Qg = qkv + (size_t)bh * NROWS * T_LEN;
  const float* __restrict__ Kg = Qg + (size_t)64 * T_LEN;
  const float* __restrict__ Vg = Qg + (size_t)128 * T_LEN;

  {
    const uint2* src = (const uint2*)(maskn + (size_t)nb * T_LEN);
    ((uint2*)Ms)[tid] = src[tid];
  }
  {
    const int c2 = (tid >> 6) * 2;
    const int s  = tid & 63;
    #pragma unroll
    for (int p = 0; p < 8; ++p) {
      int c = p * 8 + c2;
      float f0 = Qg[(size_t)c * T_LEN + t0 + s] * 0.125f;
      float f1 = Qg[(size_t)(c + 1) * T_LEN + t0 + s] * 0.125f;
      *(unsigned*)&Kt[s * KT_STRIDE + c] = pack2(f0, f1);
    }
  }
  __syncthreads();

  bf16x8 qf0 = *(const bf16x8*)&Kt[(wv * 16 + l15) * KT_STRIDE + g * 8];
  bf16x8 qf1 = *(const bf16x8*)&Kt[(wv * 16 + l15) * KT_STRIDE + 32 + g * 8];
  const int t_lane = t0 + wv * 16 + l15;
  const bool invt = (Ms[t_lane] == 0);

  f32x4 acc[4];
  #pragma unroll
  for (int i = 0; i < 4; ++i) acc[i] = (f32x4){0.f, 0.f, 0.f, 0.f};
  float m_run = -3.0e38f;
  float l_run = 0.0f;

  for (int sb = 0; sb < T_LEN / 64; ++sb) {
    const int s0 = sb * 64;
    __syncthreads();
    {
      const int c2 = (tid >> 6) * 2;
      const int s  = tid & 63;
      #pragma unroll
      for (int p = 0; p < 8; ++p) {
        int c = p * 8 + c2;
        float f0 = Kg[(size_t)c * T_LEN + s0 + s];
        float f1 = Kg[(size_t)(c + 1) * T_LEN + s0 + s];
        *(unsigned*)&Kt[s * KT_STRIDE + c] = pack2(f0, f1);
      }
    }
    {
      const int cv = (tid >> 5);
      const int s2 = tid & 31;
      #pragma unroll
      for (int p = 0; p < 8; ++p) {
        int c = p * 8 + cv;
        float2 f = *(const float2*)&Vg[(size_t)c * T_LEN + s0 + 2 * s2];
        *(unsigned*)&Vs[c * KT_STRIDE + 2 * s2] = pack2(f.x, f.y);
      }
    }
    __syncthreads();

    #pragma unroll
    for (int st = 0; st < 4; ++st) {
      const int srow = st * 16 + l15;
      bf16x8 kf0 = *(const bf16x8*)&Kt[srow * KT_STRIDE + g * 8];
      bf16x8 kf1 = *(const bf16x8*)&Kt[srow * KT_STRIDE + 32 + g * 8];
      f32x4 S = (f32x4){0.f, 0.f, 0.f, 0.f};
      S = __builtin_amdgcn_mfma_f32_16x16x32_bf16(kf0, qf0, S, 0, 0, 0);
      S = __builtin_amdgcn_mfma_f32_16x16x32_bf16(kf1, qf1, S, 0, 0, 0);

      const unsigned m4 = *(const unsigned*)&Ms[s0 + st * 16 + g * 4];
      float vals[4];
      #pragma unroll
      for (int r = 0; r < 4; ++r) {
        float x = ((m4 >> (8 * r)) & 0xffu) ? S[r] : -1.0e30f;
        vals[r] = invt ? 0.0f : x;
      }
      float pm = fmaxf(fmaxf(vals[0], vals[1]), fmaxf(vals[2], vals[3]));
      pm = fmaxf(pm, __shfl_xor(pm, 16, 64));
      pm = fmaxf(pm, __shfl_xor(pm, 32, 64));
      const float newm = fmaxf(m_run, pm);
      const float alpha = fast_exp2((m_run - newm) * 1.44269504f);
      float p0 = fast_exp2((vals[0] - newm) * 1.44269504f);
      float p1 = fast_exp2((vals[1] - newm) * 1.44269504f);
      float p2 = fast_exp2((vals[2] - newm) * 1.44269504f);
      float p3 = fast_exp2((vals[3] - newm) * 1.44269504f);
      float ps = (p0 + p1) + (p2 + p3);
      ps += __shfl_xor(ps, 16, 64);
      ps += __shfl_xor(ps, 32, 64);
      l_run = l_run * alpha + ps;
      m_run = newm;
      if (__any(alpha < 1.0f)) {
        #pragma unroll
        for (int cb = 0; cb < 4; ++cb)
          #pragma unroll
          for (int r = 0; r < 4; ++r) acc[cb][r] *= alpha;
      }
      bf16x4 pf;
      pf[0] = (short)f2bf(p0); pf[1] = (short)f2bf(p1);
      pf[2] = (short)f2bf(p2); pf[3] = (short)f2bf(p3);
      #pragma unroll
      for (int cb = 0; cb < 4; ++cb) {
        bf16x4 vf = *(const bf16x4*)&Vs[(cb * 16 + l15) * KT_STRIDE + st * 16 + g * 4];
        acc[cb] = mfma_16x16x16_bf16(vf, pf, acc[cb]);
      }
    }
  }

  const float il = 1.0f / l_run;
  const size_t out_base = (size_t)bh * 64 * T_LEN;
  #pragma unroll
  for (int cb = 0; cb < 4; ++cb) {
    #pragma unroll
    for (int r = 0; r < 4; ++r) {
      int c = cb * 16 + g * 4 + r;
      out[out_base + (size_t)c * T_LEN + t_lane] = acc[cb][r] * il;
    }
  }
}

// ---------------- launch ----------------

extern "C" void kernel_launch(void* const* d_in, const int* in_sizes, int n_in,
                              void* d_out, int out_size, void* d_ws, size_t ws_size,
                              hipStream_t stream) {
  (void)n_in; (void)out_size;
  const float* qkv = (const float*)d_in[0];
  const unsigned char* mraw = (const unsigned char*)d_in[1];
  float* out = (float*)d_out;
  const int mask_elems = in_sizes[1];   // 2*2048

  // ws layout: qtg(8 MB) | ktg tiles(9 MB) | vtg tiles(9 MB) | bias((mask_elems+2048)*4)
  const size_t QSZ = (size_t)NBH * T_LEN * 64 * sizeof(short);          // 8388608
  const size_t TSZ = (size_t)NBH * 32 * TILE_ELEMS * sizeof(short);     // 9437184
  const size_t BSZ = (size_t)(mask_elems + T_LEN) * sizeof(float);
  const size_t need = QSZ + 2 * TSZ + BSZ;
  if (ws_size >= need) {
    short* qtg = (short*)d_ws;
    short* ktg = (short*)((char*)d_ws + QSZ);
    short* vtg = (short*)((char*)d_ws + QSZ + TSZ);
    float* bias = (float*)((char*)d_ws + QSZ + 2 * TSZ);
    prep12_kernel<<<dim3(32, NBH, 4), 256, 0, stream>>>(qkv, mraw, qtg, ktg, vtg,
                                                        bias, mask_elems);
    attn11_kernel<<<dim3(NBH * 32), 512, 0, stream>>>(qtg, ktg, vtg, bias,
                                                      mask_elems, out);
  } else {
    unsigned char* maskn = (unsigned char*)d_ws;
    nm_kernel<<<(mask_elems + 255) / 256, 256, 0, stream>>>(mraw, maskn, mask_elems);
    attn_fb_kernel<<<dim3(T_LEN / QBLK, NBH), 256, 0, stream>>>(qkv, maskn, out);
  }
}

// Round 15
// 79.788 us; speedup vs baseline: 2.6529x; 1.0651x over previous
//
#include <hip/hip_runtime.h>
#include <hip/hip_bf16.h>
#include <stdint.h>

namespace {

constexpr int T_LEN = 2048;
constexpr int NROWS = 192;       // 3*64 rows per head
constexpr int QBLK  = 64;
constexpr int NBH   = 32;        // 2 batches * 16 heads
constexpr int KT_STRIDE = 72;    // padded row stride (bf16 elems) — R1/R3-validated
constexpr int TILE_ELEMS = 64 * KT_STRIDE;   // 4608 elems = 9216 B per 64-tile
constexpr int TILE_BYTES = TILE_ELEMS * 2;   // 9216 B

typedef float f32x4 __attribute__((ext_vector_type(4)));
typedef short bf16x8 __attribute__((ext_vector_type(8)));
typedef short bf16x4 __attribute__((ext_vector_type(4)));

__device__ __forceinline__ unsigned short f2bf(float f) {
  union { float f; unsigned u; } v; v.f = f;
  unsigned r = v.u + 0x7fffu + ((v.u >> 16) & 1u);   // RNE
  return (unsigned short)(r >> 16);
}
__device__ __forceinline__ unsigned pack2(float a, float b) {
  return (unsigned)f2bf(a) | ((unsigned)f2bf(b) << 16);
}
__device__ __forceinline__ float bf2f(short s) {
  union { unsigned u; float f; } v;
  v.u = ((unsigned)(unsigned short)s) << 16;
  return v.f;
}
__device__ __forceinline__ float fast_exp2(float x) {
#if __has_builtin(__builtin_amdgcn_exp2f)
  return __builtin_amdgcn_exp2f(x);
#else
  return exp2f(x);
#endif
}
__device__ __forceinline__ f32x4 mfma_16x16x16_bf16(bf16x4 a, bf16x4 b, f32x4 c) {
#if __has_builtin(__builtin_amdgcn_mfma_f32_16x16x16bf16_1k)
  return __builtin_amdgcn_mfma_f32_16x16x16bf16_1k(a, b, c, 0, 0, 0);
#else
  asm("v_mfma_f32_16x16x16_bf16 %0, %1, %2, %0" : "+v"(c) : "v"(a), "v"(b));
  return c;
#endif
}
// Async global->LDS DMA, 16B per lane: LDS dest = wave-uniform base + lane*16.
__device__ __forceinline__ void gload_lds16(const void* g, void* l) {
  __builtin_amdgcn_global_load_lds(
      (const __attribute__((address_space(1))) unsigned int*)g,
      (__attribute__((address_space(3))) unsigned int*)l, 16, 0, 0);
}

} // namespace

// Normalize mask to uint8 (fallback path). Stride detect via guaranteed-true mask[0][1].
__global__ void nm_kernel(const unsigned char* __restrict__ raw,
                          unsigned char* __restrict__ outm, int n) {
  int stride = (raw[1] != 0) ? 1 : ((raw[4] != 0) ? 4 : 8);
  int i = blockIdx.x * blockDim.x + threadIdx.x;
  if (i < n) outm[i] = (raw[(size_t)i * stride] != 0) ? 1 : 0;
}

// ---------------- merged prepass (R12/R13/R14-validated): ONE launch ---------------
// grid (32, NBH, 4), 256 thr.
// z==0: Q -> [bh][t][64] linear, scaled 0.125*log2(e), masked-t rows zeroed.
// z==1: K -> [bh][sb][64][72] tiles.
// z>=2: V -> [bh][sb][64][72] tiles; z==2,bh==0,bx<24 also emit bias table
//        (mask_elems entries {0,-1e30} + T_LEN zero row).
__global__ __launch_bounds__(256) void prep12_kernel(const float* __restrict__ qkv,
                                                     const unsigned char* __restrict__ mraw,
                                                     short* __restrict__ qtg,
                                                     short* __restrict__ ktg,
                                                     short* __restrict__ vtg,
                                                     float* __restrict__ bias,
                                                     int mask_elems) {
  const int z  = blockIdx.z;
  const int bh = blockIdx.y;
  const int bx = blockIdx.x;
  const int t  = threadIdx.x;

  if (z >= 2) {
    int cid = ((bh * 64) + (z - 2) * 32 + bx) * 256 + t;
    int bh2 = cid >> 14;
    int rem = cid & 16383;
    int c = rem >> 8;
    int cg = rem & 255;
    int grp = cg >> 3, jin = cg & 7;
    const float* src = qkv + (size_t)bh2 * NROWS * T_LEN + (size_t)(128 + c) * T_LEN + cg * 8;
    float4 a = *(const float4*)src;
    float4 b = *(const float4*)(src + 4);
    bf16x4 o0, o1;
    o0[0] = (short)f2bf(a.x); o0[1] = (short)f2bf(a.y);
    o0[2] = (short)f2bf(a.z); o0[3] = (short)f2bf(a.w);
    o1[0] = (short)f2bf(b.x); o1[1] = (short)f2bf(b.y);
    o1[2] = (short)f2bf(b.z); o1[3] = (short)f2bf(b.w);
    short* d = vtg + (size_t)(bh2 * 32 + grp) * TILE_ELEMS + c * KT_STRIDE + jin * 8;
    *(bf16x4*)d = o0;
    *(bf16x4*)(d + 4) = o1;
    if (z == 2 && bh == 0 && bx < 24) {
      int i = bx * 256 + t;
      int stride = (mraw[1] != 0) ? 1 : ((mraw[4] != 0) ? 4 : 8);
      if (i < mask_elems) bias[i] = (mraw[(size_t)i * stride] != 0) ? 0.0f : -1.0e30f;
      else if (i < mask_elems + T_LEN) bias[i] = 0.0f;
    }
    return;
  }

  __shared__ float tile[64][65];
  const int s0 = bx * 64;
  const float* src = qkv + (size_t)bh * NROWS * T_LEN + (size_t)z * 64 * T_LEN;
  const int c = t >> 2;
  #pragma unroll
  for (int p = 0; p < 4; ++p) {
    int col = (t & 3) * 4 + p * 16;
    float4 v = *(const float4*)&src[(size_t)c * T_LEN + s0 + col];
    tile[c][col] = v.x; tile[c][col + 1] = v.y;
    tile[c][col + 2] = v.z; tile[c][col + 3] = v.w;
  }
  __syncthreads();
  const int s = t & 63;
  float scale;
  if (z) {
    scale = 1.0f;
  } else {
    const int mstride = (mraw[1] != 0) ? 1 : ((mraw[4] != 0) ? 4 : 8);
    const int nb = bh >> 4;
    const bool live = mraw[((size_t)nb * T_LEN + s0 + s) * mstride] != 0;
    scale = live ? 0.18033688011112042f : 0.0f;   // 0.125*log2(e), 0 for masked t
  }
  #pragma unroll
  for (int p = 0; p < 2; ++p) {
    int jc = (t >> 6) * 2 + p;
    bf16x4 o0, o1;
    #pragma unroll
    for (int i = 0; i < 4; ++i) {
      o0[i] = (short)f2bf(tile[jc * 8 + i][s] * scale);
      o1[i] = (short)f2bf(tile[jc * 8 + 4 + i][s] * scale);
    }
    short* d = z
      ? (ktg + (size_t)(bh * 32 + bx) * TILE_ELEMS + s * KT_STRIDE + jc * 8)
      : (qtg + (size_t)bh * T_LEN * 64 + (size_t)(s0 + s) * 64 + jc * 8);
    *(bf16x4*)d = o0;
    *(bf16x4*)(d + 4) = o1;
  }
}

// ------ attn15: R11 math + T4 counted-vmcnt pipeline. 3-deep K/V LDS ring; DMA for
// tile i+2 issued at iter i, consumed at iter i+2 (2 compute phases of latency cover).
// Loop sync = s_waitcnt vmcnt(n_tile) + raw s_barrier (never drain-0 until tail).
// Bias staged in LDS as bf16 so in-loop vmem ops are EXACTLY the DMA (counts valid).
// Masking: fma(b4, live, S) — attn13-validated numerics.

__global__ __launch_bounds__(512, 4) void attn15_kernel(const short* __restrict__ qtg,
                                                        const short* __restrict__ ktg,
                                                        const short* __restrict__ vtg,
                                                        const float* __restrict__ bias,
                                                        float* __restrict__ out) {
  // K ring [0,3)*TILE | V ring [3,6)*TILE | bias bf16 row (2048 shorts) = 59392 B
  __shared__ __align__(16) short smem[6 * TILE_ELEMS + T_LEN];

  const int tid  = threadIdx.x;
  const int lane = tid & 63;
  const int wv   = tid >> 6;    // 0..7
  const int sgrp = wv & 3;      // owns st = sgrp
  const int tgrp = wv >> 2;     // owns tw = {2*tgrp, 2*tgrp+1}
  const int l15  = lane & 15;
  const int g    = lane >> 4;

  int id = blockIdx.x;
  id = (id & 7) * 128 + (id >> 3);   // bijective XCD swizzle (bit-rotation)
  const int bh = id >> 5;
  const int t0 = (id & 31) * QBLK;
  const int nb = bh >> 4;

  const int tA = t0 + tgrp * 32 + l15;
  const int tB = tA + 16;

  // Q fragments (masked-t rows pre-zeroed by prep12)
  const short* Qbase = qtg + (size_t)bh * T_LEN * 64;
  const bf16x8 qfA0 = *(const bf16x8*)(Qbase + (size_t)tA * 64 + g * 8);
  const bf16x8 qfA1 = *(const bf16x8*)(Qbase + (size_t)tA * 64 + 32 + g * 8);
  const bf16x8 qfB0 = *(const bf16x8*)(Qbase + (size_t)tB * 64 + g * 8);
  const bf16x8 qfB1 = *(const bf16x8*)(Qbase + (size_t)tB * 64 + 32 + g * 8);

  // live flags (masked t -> 0 -> bias contribution nulled -> S=0 -> p=1 uniform)
  const float liveA = (bias[(size_t)nb * T_LEN + tA] == 0.0f) ? 1.0f : 0.0f;
  const float liveB = (bias[(size_t)nb * T_LEN + tB] == 0.0f) ? 1.0f : 0.0f;

  char* KtL = (char*)smem;
  char* VsL = (char*)smem + 3 * TILE_BYTES;
  short* biasL = smem + 6 * TILE_ELEMS;

  // stage bias row to LDS as bf16 (512 thr x 4 elems)
  {
    f32x4 bv = *(const f32x4*)&bias[(size_t)nb * T_LEN + tid * 4];
    union { bf16x4 v; __hip_bfloat162 h[2]; } bb;
    bb.h[0] = __float22bfloat162_rn(float2{bv[0], bv[1]});
    bb.h[1] = __float22bfloat162_rn(float2{bv[2], bv[3]});
    *(bf16x4*)&biasL[tid * 4] = bb.v;
  }

  const char* __restrict__ kt0 = (const char*)(ktg + (size_t)bh * 32 * TILE_ELEMS);
  const char* __restrict__ vt0 = (const char*)(vtg + (size_t)bh * 32 * TILE_ELEMS);

  // per-tile DMA: waves 0,1 issue 3 ops; waves 2-7 issue 2 ops (order fixed).
  auto ISSUE = [&](int j, int r) {
    const char* ks = kt0 + (size_t)j * TILE_BYTES;
    const char* vs = vt0 + (size_t)j * TILE_BYTES;
    char* kd = KtL + r * TILE_BYTES;
    char* vd = VsL + r * TILE_BYTES;
    gload_lds16(ks + wv * 1024 + lane * 16, kd + wv * 1024);
    gload_lds16(vs + wv * 1024 + lane * 16, vd + wv * 1024);
    if (wv == 0) gload_lds16(ks + 8192 + lane * 16, kd + 8192);
    if (wv == 1) gload_lds16(vs + 8192 + lane * 16, vd + 8192);
  };

  // prologue: tiles 0,1 in flight; wait tile0 (keep tile1's n outstanding) + bias
  ISSUE(0, 0);
  ISSUE(1, 1);
  if (wv < 2) asm volatile("s_waitcnt vmcnt(3) lgkmcnt(0)" ::: "memory");
  else        asm volatile("s_waitcnt vmcnt(2) lgkmcnt(0)" ::: "memory");
  __builtin_amdgcn_s_barrier();

  f32x4 accA[4], accB[4];
  #pragma unroll
  for (int i = 0; i < 4; ++i) { accA[i] = (f32x4){0.f,0.f,0.f,0.f}; accB[i] = accA[i]; }
  float lA = 0.0f, lB = 0.0f;

  const int koff = (sgrp * 16 + l15) * KT_STRIDE;
  const int boff = sgrp * 16 + g * 4;

  int ring = 0;
  for (int sb = 0; sb < T_LEN / 64; ++sb) {
    // issue tile sb+2 into ring slot (ring+2)%3 — buffer was freed at barrier sb-1
    if (sb + 2 < T_LEN / 64) {
      int r2 = ring + 2; if (r2 >= 3) r2 -= 3;
      ISSUE(sb + 2, r2);
    }

    const short* Ktc = (const short*)(KtL + ring * TILE_BYTES);
    const short* Vsc = (const short*)(VsL + ring * TILE_BYTES);

    // K fragment read ONCE per wave, shared by both t-windows
    bf16x8 kf0 = *(const bf16x8*)&Ktc[koff + g * 8];
    bf16x8 kf1 = *(const bf16x8*)&Ktc[koff + 32 + g * 8];

    f32x4 SA = (f32x4){0.f, 0.f, 0.f, 0.f};
    SA = __builtin_amdgcn_mfma_f32_16x16x32_bf16(kf0, qfA0, SA, 0, 0, 0);
    SA = __builtin_amdgcn_mfma_f32_16x16x32_bf16(kf1, qfA1, SA, 0, 0, 0);
    f32x4 SB = (f32x4){0.f, 0.f, 0.f, 0.f};
    SB = __builtin_amdgcn_mfma_f32_16x16x32_bf16(kf0, qfB0, SB, 0, 0, 0);
    SB = __builtin_amdgcn_mfma_f32_16x16x32_bf16(kf1, qfB1, SB, 0, 0, 0);

    // bias from LDS (bf16 -> f32), applied via live flag (attn13-validated)
    const bf16x4 braw = *(const bf16x4*)&biasL[sb * 64 + boff];
    const float b0 = bf2f(braw[0]), b1 = bf2f(braw[1]);
    const float b2 = bf2f(braw[2]), b3 = bf2f(braw[3]);
    float pA0 = fast_exp2(__builtin_fmaf(b0, liveA, SA[0]));
    float pA1 = fast_exp2(__builtin_fmaf(b1, liveA, SA[1]));
    float pA2 = fast_exp2(__builtin_fmaf(b2, liveA, SA[2]));
    float pA3 = fast_exp2(__builtin_fmaf(b3, liveA, SA[3]));
    lA += (pA0 + pA1) + (pA2 + pA3);
    float pB0 = fast_exp2(__builtin_fmaf(b0, liveB, SB[0]));
    float pB1 = fast_exp2(__builtin_fmaf(b1, liveB, SB[1]));
    float pB2 = fast_exp2(__builtin_fmaf(b2, liveB, SB[2]));
    float pB3 = fast_exp2(__builtin_fmaf(b3, liveB, SB[3]));
    lB += (pB0 + pB1) + (pB2 + pB3);

    union { bf16x4 v; __hip_bfloat162 h[2]; } pfA, pfB;
    pfA.h[0] = __float22bfloat162_rn(float2{pA0, pA1});
    pfA.h[1] = __float22bfloat162_rn(float2{pA2, pA3});
    pfB.h[0] = __float22bfloat162_rn(float2{pB0, pB1});
    pfB.h[1] = __float22bfloat162_rn(float2{pB2, pB3});

    // V fragment read ONCE per cb, shared by both t-windows
    #pragma unroll
    for (int cb = 0; cb < 4; ++cb) {
      bf16x4 vf = *(const bf16x4*)&Vsc[(cb * 16 + l15) * KT_STRIDE + sgrp * 16 + g * 4];
      accA[cb] = mfma_16x16x16_bf16(vf, pfA.v, accA[cb]);
      accB[cb] = mfma_16x16x16_bf16(vf, pfB.v, accB[cb]);
    }

    // T4 counted wait: retire tile sb+1 (older), keep tile sb+2's n ops in flight.
    // FIFO vmcnt: tile sb+1 ops are strictly older than tile sb+2's n ops.
    if (sb < T_LEN / 64 - 2) {
      if (wv < 2) asm volatile("s_waitcnt vmcnt(3)" ::: "memory");
      else        asm volatile("s_waitcnt vmcnt(2)" ::: "memory");
    } else {
      asm volatile("s_waitcnt vmcnt(0)" ::: "memory");
    }
    __builtin_amdgcn_s_barrier();
    ring = (ring == 2) ? 0 : ring + 1;
  }

  // ---- 4-partial combine over sgrp (two-round tree, R11-verbatim; scratch fits
  // in first 36864 B of smem). Slot: 64 lanes x 36 floats; 4 slots.
  float* scr = (float*)smem;
  {
    const int lb = lane * 36;
    if (sgrp >= 2) {
      float* base = scr + ((sgrp - 2) * 2 + tgrp) * 2304 + lb;
      #pragma unroll
      for (int cb = 0; cb < 4; ++cb) {
        *(f32x4*)&base[cb * 4] = accA[cb];
        *(f32x4*)&base[16 + cb * 4] = accB[cb];
      }
      base[32] = lA; base[33] = lB;
    }
    __syncthreads();
    if (sgrp < 2) {
      const float* base = scr + (sgrp * 2 + tgrp) * 2304 + lb;
      #pragma unroll
      for (int cb = 0; cb < 4; ++cb) {
        accA[cb] += *(const f32x4*)&base[cb * 4];
        accB[cb] += *(const f32x4*)&base[16 + cb * 4];
      }
      lA += base[32]; lB += base[33];
    }
    __syncthreads();
    if (sgrp == 1) {
      float* base = scr + tgrp * 2304 + lb;
      #pragma unroll
      for (int cb = 0; cb < 4; ++cb) {
        *(f32x4*)&base[cb * 4] = accA[cb];
        *(f32x4*)&base[16 + cb * 4] = accB[cb];
      }
      base[32] = lA; base[33] = lB;
    }
    __syncthreads();
    if (sgrp == 0) {
      const float* base = scr + tgrp * 2304 + lb;
      #pragma unroll
      for (int cb = 0; cb < 4; ++cb) {
        accA[cb] += *(const f32x4*)&base[cb * 4];
        accB[cb] += *(const f32x4*)&base[16 + cb * 4];
      }
      lA += base[32]; lB += base[33];

      lA += __shfl_xor(lA, 16, 64);
      lA += __shfl_xor(lA, 32, 64);
      lB += __shfl_xor(lB, 16, 64);
      lB += __shfl_xor(lB, 32, 64);
      const float ilA = 1.0f / lA;
      const float ilB = 1.0f / lB;
      const size_t out_base = (size_t)bh * 64 * T_LEN;
      #pragma unroll
      for (int cb = 0; cb < 4; ++cb) {
        #pragma unroll
        for (int r = 0; r < 4; ++r) {
          int c = cb * 16 + g * 4 + r;
          out[out_base + (size_t)c * T_LEN + tA] = accA[cb][r] * ilA;
          out[out_base + (size_t)c * T_LEN + tB] = accB[cb][r] * ilB;
        }
      }
    }
  }
}

// ---------------- fallback path (round-1 kernel, used if ws too small) ------------

__global__ __launch_bounds__(256) void attn_fb_kernel(const float* __restrict__ qkv,
                                                      const unsigned char* __restrict__ maskn,
                                                      float* __restrict__ out) {
  __shared__ __align__(16) short Kt[QBLK * KT_STRIDE];
  __shared__ __align__(16) short Vs[64 * KT_STRIDE];
  __shared__ __align__(16) unsigned char Ms[T_LEN];

  const int tid  = threadIdx.x;
  const int lane = tid & 63;
  const int wv   = tid >> 6;
  const int l15  = lane & 15;
  const int g    = lane >> 4;

  const int bh = blockIdx.y;
  const int nb = bh >> 4;
  const int t0 = blockIdx.x * QBLK;

  const float* __restrict__ Qg = qkv + (size_t)bh * NROWS * T_LEN;
  const float* __restrict__ Kg = Qg + (size_t)64 * T_LEN;
  const float* __restrict__ Vg = Qg + (size_t)128 * T_LEN;

  {
    const uint2* src = (const uint2*)(maskn + (size_t)nb * T_LEN);
    ((uint2*)Ms)[tid] = src[tid];
  }
  {
    const int c2 = (tid >> 6) * 2;
    const int s  = tid & 63;
    #pragma unroll
    for (int p = 0; p < 8; ++p) {
      int c = p * 8 + c2;
      float f0 = Qg[(size_t)c * T_LEN + t0 + s] * 0.125f;
      float f1 = Qg[(size_t)(c + 1) * T_LEN + t0 + s] * 0.125f;
      *(unsigned*)&Kt[s * KT_STRIDE + c] = pack2(f0, f1);
    }
  }
  __syncthreads();

  bf16x8 qf0 = *(const bf16x8*)&Kt[(wv * 16 + l15) * KT_STRIDE + g * 8];
  bf16x8 qf1 = *(const bf16x8*)&Kt[(wv * 16 + l15) * KT_STRIDE + 32 + g * 8];
  const int t_lane = t0 + wv * 16 + l15;
  const bool invt = (Ms[t_lane] == 0);

  f32x4 acc[4];
  #pragma unroll
  for (int i = 0; i < 4; ++i) acc[i] = (f32x4){0.f, 0.f, 0.f, 0.f};
  float m_run = -3.0e38f;
  float l_run = 0.0f;

  for (int sb = 0; sb < T_LEN / 64; ++sb) {
    const int s0 = sb * 64;
    __syncthreads();
    {
      const int c2 = (tid >> 6) * 2;
      const int s  = tid & 63;
      #pragma unroll
      for (int p = 0; p < 8; ++p) {
        int c = p * 8 + c2;
        float f0 = Kg[(size_t)c * T_LEN + s0 + s];
        float f1 = Kg[(size_t)(c + 1) * T_LEN + s0 + s];
        *(unsigned*)&Kt[s * KT_STRIDE + c] = pack2(f0, f1);
      }
    }
    {
      const int cv = (tid >> 5);
      const int s2 = tid & 31;
      #pragma unroll
      for (int p = 0; p < 8; ++p) {
        int c = p * 8 + cv;
        float2 f = *(const float2*)&Vg[(size_t)c * T_LEN + s0 + 2 * s2];
        *(unsigned*)&Vs[c * KT_STRIDE + 2 * s2] = pack2(f.x, f.y);
      }
    }
    __syncthreads();

    #pragma unroll
    for (int st = 0; st < 4; ++st) {
      const int srow = st * 16 + l15;
      bf16x8 kf0 = *(const bf16x8*)&Kt[srow * KT_STRIDE + g * 8];
      bf16x8 kf1 = *(const bf16x8*)&Kt[srow * KT_STRIDE + 32 + g * 8];
      f32x4 S = (f32x4){0.f, 0.f, 0.f, 0.f};
      S = __builtin_amdgcn_mfma_f32_16x16x32_bf16(kf0, qf0, S, 0, 0, 0);
      S = __builtin_amdgcn_mfma_f32_16x16x32_bf16(kf1, qf1, S, 0, 0, 0);

      const unsigned m4 = *(const unsigned*)&Ms[s0 + st * 16 + g * 4];
      float vals[4];
      #pragma unroll
      for (int r = 0; r < 4; ++r) {
        float x = ((m4 >> (8 * r)) & 0xffu) ? S[r] : -1.0e30f;
        vals[r] = invt ? 0.0f : x;
      }
      float pm = fmaxf(fmaxf(vals[0], vals[1]), fmaxf(vals[2], vals[3]));
      pm = fmaxf(pm, __shfl_xor(pm, 16, 64));
      pm = fmaxf(pm, __shfl_xor(pm, 32, 64));
      const float newm = fmaxf(m_run, pm);
      const float alpha = fast_exp2((m_run - newm) * 1.44269504f);
      float p0 = fast_exp2((vals[0] - newm) * 1.44269504f);
      float p1 = fast_exp2((vals[1] - newm) * 1.44269504f);
      float p2 = fast_exp2((vals[2] - newm) * 1.44269504f);
      float p3 = fast_exp2((vals[3] - newm) * 1.44269504f);
      float ps = (p0 + p1) + (p2 + p3);
      ps += __shfl_xor(ps, 16, 64);
      ps += __shfl_xor(ps, 32, 64);
      l_run = l_run * alpha + ps;
      m_run = newm;
      if (__any(alpha < 1.0f)) {
        #pragma unroll
        for (int cb = 0; cb < 4; ++cb)
          #pragma unroll
          for (int r = 0; r < 4; ++r) acc[cb][r] *= alpha;
      }
      bf16x4 pf;
      pf[0] = (short)f2bf(p0); pf[1] = (short)f2bf(p1);
      pf[2] = (short)f2bf(p2); pf[3] = (short)f2bf(p3);
      #pragma unroll
      for (int cb = 0; cb < 4; ++cb) {
        bf16x4 vf = *(const bf16x4*)&Vs[(cb * 16 + l15) * KT_STRIDE + st * 16 + g * 4];
        acc[cb] = mfma_16x16x16_bf16(vf, pf, acc[cb]);
      }
    }
  }

  const float il = 1.0f / l_run;
  const size_t out_base = (size_t)bh * 64 * T_LEN;
  #pragma unroll
  for (int cb = 0; cb < 4; ++cb) {
    #pragma unroll
    for (int r = 0; r < 4; ++r) {
      int c = cb * 16 + g * 4 + r;
      out[out_base + (size_t)c * T_LEN + t_lane] = acc[cb][r] * il;
    }
  }
}

// ---------------- launch ----------------

extern "C" void kernel_launch(void* const* d_in, const int* in_sizes, int n_in,
                              void* d_out, int out_size, void* d_ws, size_t ws_size,
                              hipStream_t stream) {
  (void)n_in; (void)out_size;
  const float* qkv = (const float*)d_in[0];
  const unsigned char* mraw = (const unsigned char*)d_in[1];
  float* out = (float*)d_out;
  const int mask_elems = in_sizes[1];   // 2*2048

  // ws layout: qtg(8 MB) | ktg tiles(9 MB) | vtg tiles(9 MB) | bias((mask_elems+2048)*4)
  const size_t QSZ = (size_t)NBH * T_LEN * 64 * sizeof(short);          // 8388608
  const size_t TSZ = (size_t)NBH * 32 * TILE_ELEMS * sizeof(short);     // 9437184
  const size_t BSZ = (size_t)(mask_elems + T_LEN) * sizeof(float);
  const size_t need = QSZ + 2 * TSZ + BSZ;
  if (ws_size >= need) {
    short* qtg = (short*)d_ws;
    short* ktg = (short*)((char*)d_ws + QSZ);
    short* vtg = (short*)((char*)d_ws + QSZ + TSZ);
    float* bias = (float*)((char*)d_ws + QSZ + 2 * TSZ);
    prep12_kernel<<<dim3(32, NBH, 4), 256, 0, stream>>>(qkv, mraw, qtg, ktg, vtg,
                                                        bias, mask_elems);
    attn15_kernel<<<dim3(NBH * 32), 512, 0, stream>>>(qtg, ktg, vtg, bias, out);
  } else {
    unsigned char* maskn = (unsigned char*)d_ws;
    nm_kernel<<<(mask_elems + 255) / 256, 256, 0, stream>>>(mraw, maskn, mask_elems);
    attn_fb_kernel<<<dim3(T_LEN / QBLK, NBH), 256, 0, stream>>>(qkv, maskn, out);
  }
}

// Round 16
// 79.646 us; speedup vs baseline: 2.6577x; 1.0018x over previous
//
#include <hip/hip_runtime.h>
#include <hip/hip_bf16.h>
#include <stdint.h>

namespace {

constexpr int T_LEN = 2048;
constexpr int NROWS = 192;       // 3*64 rows per head
constexpr int QBLK  = 64;
constexpr int NBH   = 32;        // 2 batches * 16 heads
constexpr int KT_STRIDE = 72;    // padded row stride (bf16 elems) — R1/R3-validated
constexpr int TILE_ELEMS = 64 * KT_STRIDE;   // 4608 elems = 9216 B per 64-tile
constexpr int TILE_BYTES = TILE_ELEMS * 2;   // 9216 B
constexpr int NT = T_LEN / 64;               // 32 tiles

typedef float f32x4 __attribute__((ext_vector_type(4)));
typedef short bf16x8 __attribute__((ext_vector_type(8)));
typedef short bf16x4 __attribute__((ext_vector_type(4)));

__device__ __forceinline__ unsigned short f2bf(float f) {
  union { float f; unsigned u; } v; v.f = f;
  unsigned r = v.u + 0x7fffu + ((v.u >> 16) & 1u);   // RNE
  return (unsigned short)(r >> 16);
}
__device__ __forceinline__ unsigned pack2(float a, float b) {
  return (unsigned)f2bf(a) | ((unsigned)f2bf(b) << 16);
}
__device__ __forceinline__ float bf2f(short s) {
  union { unsigned u; float f; } v;
  v.u = ((unsigned)(unsigned short)s) << 16;
  return v.f;
}
__device__ __forceinline__ float fast_exp2(float x) {
#if __has_builtin(__builtin_amdgcn_exp2f)
  return __builtin_amdgcn_exp2f(x);
#else
  return exp2f(x);
#endif
}
__device__ __forceinline__ f32x4 mfma_16x16x16_bf16(bf16x4 a, bf16x4 b, f32x4 c) {
#if __has_builtin(__builtin_amdgcn_mfma_f32_16x16x16bf16_1k)
  return __builtin_amdgcn_mfma_f32_16x16x16bf16_1k(a, b, c, 0, 0, 0);
#else
  asm("v_mfma_f32_16x16x16_bf16 %0, %1, %2, %0" : "+v"(c) : "v"(a), "v"(b));
  return c;
#endif
}
// Async global->LDS DMA, 16B per lane: LDS dest = wave-uniform base + lane*16.
__device__ __forceinline__ void gload_lds16(const void* g, void* l) {
  __builtin_amdgcn_global_load_lds(
      (const __attribute__((address_space(1))) unsigned int*)g,
      (__attribute__((address_space(3))) unsigned int*)l, 16, 0, 0);
}

} // namespace

// Normalize mask to uint8 (fallback path). Stride detect via guaranteed-true mask[0][1].
__global__ void nm_kernel(const unsigned char* __restrict__ raw,
                          unsigned char* __restrict__ outm, int n) {
  int stride = (raw[1] != 0) ? 1 : ((raw[4] != 0) ? 4 : 8);
  int i = blockIdx.x * blockDim.x + threadIdx.x;
  if (i < n) outm[i] = (raw[(size_t)i * stride] != 0) ? 1 : 0;
}

// ---------------- merged prepass (R12-R15-validated): ONE launch -------------------
__global__ __launch_bounds__(256) void prep12_kernel(const float* __restrict__ qkv,
                                                     const unsigned char* __restrict__ mraw,
                                                     short* __restrict__ qtg,
                                                     short* __restrict__ ktg,
                                                     short* __restrict__ vtg,
                                                     float* __restrict__ bias,
                                                     int mask_elems) {
  const int z  = blockIdx.z;
  const int bh = blockIdx.y;
  const int bx = blockIdx.x;
  const int t  = threadIdx.x;

  if (z >= 2) {
    int cid = ((bh * 64) + (z - 2) * 32 + bx) * 256 + t;
    int bh2 = cid >> 14;
    int rem = cid & 16383;
    int c = rem >> 8;
    int cg = rem & 255;
    int grp = cg >> 3, jin = cg & 7;
    const float* src = qkv + (size_t)bh2 * NROWS * T_LEN + (size_t)(128 + c) * T_LEN + cg * 8;
    float4 a = *(const float4*)src;
    float4 b = *(const float4*)(src + 4);
    bf16x4 o0, o1;
    o0[0] = (short)f2bf(a.x); o0[1] = (short)f2bf(a.y);
    o0[2] = (short)f2bf(a.z); o0[3] = (short)f2bf(a.w);
    o1[0] = (short)f2bf(b.x); o1[1] = (short)f2bf(b.y);
    o1[2] = (short)f2bf(b.z); o1[3] = (short)f2bf(b.w);
    short* d = vtg + (size_t)(bh2 * 32 + grp) * TILE_ELEMS + c * KT_STRIDE + jin * 8;
    *(bf16x4*)d = o0;
    *(bf16x4*)(d + 4) = o1;
    if (z == 2 && bh == 0 && bx < 24) {
      int i = bx * 256 + t;
      int stride = (mraw[1] != 0) ? 1 : ((mraw[4] != 0) ? 4 : 8);
      if (i < mask_elems) bias[i] = (mraw[(size_t)i * stride] != 0) ? 0.0f : -1.0e30f;
      else if (i < mask_elems + T_LEN) bias[i] = 0.0f;
    }
    return;
  }

  __shared__ float tile[64][65];
  const int s0 = bx * 64;
  const float* src = qkv + (size_t)bh * NROWS * T_LEN + (size_t)z * 64 * T_LEN;
  const int c = t >> 2;
  #pragma unroll
  for (int p = 0; p < 4; ++p) {
    int col = (t & 3) * 4 + p * 16;
    float4 v = *(const float4*)&src[(size_t)c * T_LEN + s0 + col];
    tile[c][col] = v.x; tile[c][col + 1] = v.y;
    tile[c][col + 2] = v.z; tile[c][col + 3] = v.w;
  }
  __syncthreads();
  const int s = t & 63;
  float scale;
  if (z) {
    scale = 1.0f;
  } else {
    const int mstride = (mraw[1] != 0) ? 1 : ((mraw[4] != 0) ? 4 : 8);
    const int nb = bh >> 4;
    const bool live = mraw[((size_t)nb * T_LEN + s0 + s) * mstride] != 0;
    scale = live ? 0.18033688011112042f : 0.0f;   // 0.125*log2(e), 0 for masked t
  }
  #pragma unroll
  for (int p = 0; p < 2; ++p) {
    int jc = (t >> 6) * 2 + p;
    bf16x4 o0, o1;
    #pragma unroll
    for (int i = 0; i < 4; ++i) {
      o0[i] = (short)f2bf(tile[jc * 8 + i][s] * scale);
      o1[i] = (short)f2bf(tile[jc * 8 + 4 + i][s] * scale);
    }
    short* d = z
      ? (ktg + (size_t)(bh * 32 + bx) * TILE_ELEMS + s * KT_STRIDE + jc * 8)
      : (qtg + (size_t)bh * T_LEN * 64 + (size_t)(s0 + s) * 64 + jc * 8);
    *(bf16x4*)d = o0;
    *(bf16x4*)(d + 4) = o1;
  }
}

// ------ attn16: attn15 + 4-deep ring (issue i+3, wait keeps TWO tiles in flight:
// vmcnt(2n)) + T5 s_setprio around MFMA clusters. All math attn15/R11-verbatim.

__global__ __launch_bounds__(512, 4) void attn16_kernel(const short* __restrict__ qtg,
                                                        const short* __restrict__ ktg,
                                                        const short* __restrict__ vtg,
                                                        const float* __restrict__ bias,
                                                        float* __restrict__ out) {
  // K ring [0,4)*TILE | V ring [4,8)*TILE | bias bf16 row = 77824 B (2 blocks/CU)
  __shared__ __align__(16) short smem[8 * TILE_ELEMS + T_LEN];

  const int tid  = threadIdx.x;
  const int lane = tid & 63;
  const int wv   = tid >> 6;    // 0..7
  const int sgrp = wv & 3;      // owns st = sgrp
  const int tgrp = wv >> 2;     // owns tw = {2*tgrp, 2*tgrp+1}
  const int l15  = lane & 15;
  const int g    = lane >> 4;

  int id = blockIdx.x;
  id = (id & 7) * 128 + (id >> 3);   // bijective XCD swizzle (bit-rotation)
  const int bh = id >> 5;
  const int t0 = (id & 31) * QBLK;
  const int nb = bh >> 4;

  const int tA = t0 + tgrp * 32 + l15;
  const int tB = tA + 16;

  // Q fragments (masked-t rows pre-zeroed by prep12)
  const short* Qbase = qtg + (size_t)bh * T_LEN * 64;
  const bf16x8 qfA0 = *(const bf16x8*)(Qbase + (size_t)tA * 64 + g * 8);
  const bf16x8 qfA1 = *(const bf16x8*)(Qbase + (size_t)tA * 64 + 32 + g * 8);
  const bf16x8 qfB0 = *(const bf16x8*)(Qbase + (size_t)tB * 64 + g * 8);
  const bf16x8 qfB1 = *(const bf16x8*)(Qbase + (size_t)tB * 64 + 32 + g * 8);

  // live flags (masked t -> 0 -> bias nulled -> S=0 -> p=1 uniform)
  const float liveA = (bias[(size_t)nb * T_LEN + tA] == 0.0f) ? 1.0f : 0.0f;
  const float liveB = (bias[(size_t)nb * T_LEN + tB] == 0.0f) ? 1.0f : 0.0f;

  char* KtL = (char*)smem;
  char* VsL = (char*)smem + 4 * TILE_BYTES;
  short* biasL = smem + 8 * TILE_ELEMS;

  // stage bias row to LDS as bf16 (512 thr x 4 elems)
  {
    f32x4 bv = *(const f32x4*)&bias[(size_t)nb * T_LEN + tid * 4];
    union { bf16x4 v; __hip_bfloat162 h[2]; } bb;
    bb.h[0] = __float22bfloat162_rn(float2{bv[0], bv[1]});
    bb.h[1] = __float22bfloat162_rn(float2{bv[2], bv[3]});
    *(bf16x4*)&biasL[tid * 4] = bb.v;
  }

  const char* __restrict__ kt0 = (const char*)(ktg + (size_t)bh * 32 * TILE_ELEMS);
  const char* __restrict__ vt0 = (const char*)(vtg + (size_t)bh * 32 * TILE_ELEMS);

  // per-tile DMA: waves 0,1 issue 3 ops; waves 2-7 issue 2 ops (order fixed).
  auto ISSUE = [&](int j, int r) {
    const char* ks = kt0 + (size_t)j * TILE_BYTES;
    const char* vs = vt0 + (size_t)j * TILE_BYTES;
    char* kd = KtL + r * TILE_BYTES;
    char* vd = VsL + r * TILE_BYTES;
    gload_lds16(ks + wv * 1024 + lane * 16, kd + wv * 1024);
    gload_lds16(vs + wv * 1024 + lane * 16, vd + wv * 1024);
    if (wv == 0) gload_lds16(ks + 8192 + lane * 16, kd + 8192);
    if (wv == 1) gload_lds16(vs + 8192 + lane * 16, vd + 8192);
  };

  // prologue: tiles 0,1,2 in flight; wait tile0 (keep tiles 1,2 = 2n outstanding)
  ISSUE(0, 0);
  ISSUE(1, 1);
  ISSUE(2, 2);
  if (wv < 2) asm volatile("s_waitcnt vmcnt(6) lgkmcnt(0)" ::: "memory");
  else        asm volatile("s_waitcnt vmcnt(4) lgkmcnt(0)" ::: "memory");
  __builtin_amdgcn_s_barrier();

  f32x4 accA[4], accB[4];
  #pragma unroll
  for (int i = 0; i < 4; ++i) { accA[i] = (f32x4){0.f,0.f,0.f,0.f}; accB[i] = accA[i]; }
  float lA = 0.0f, lB = 0.0f;

  const int koff = (sgrp * 16 + l15) * KT_STRIDE;
  const int boff = sgrp * 16 + g * 4;

  int ring = 0;
  for (int sb = 0; sb < NT; ++sb) {
    // issue tile sb+3 into ring slot (ring+3)&3 — freed at barrier sb-1
    if (sb + 3 < NT) ISSUE(sb + 3, (ring + 3) & 3);

    const short* Ktc = (const short*)(KtL + ring * TILE_BYTES);
    const short* Vsc = (const short*)(VsL + ring * TILE_BYTES);

    bf16x8 kf0 = *(const bf16x8*)&Ktc[koff + g * 8];
    bf16x8 kf1 = *(const bf16x8*)&Ktc[koff + 32 + g * 8];

    __builtin_amdgcn_s_setprio(1);
    f32x4 SA = (f32x4){0.f, 0.f, 0.f, 0.f};
    SA = __builtin_amdgcn_mfma_f32_16x16x32_bf16(kf0, qfA0, SA, 0, 0, 0);
    SA = __builtin_amdgcn_mfma_f32_16x16x32_bf16(kf1, qfA1, SA, 0, 0, 0);
    f32x4 SB = (f32x4){0.f, 0.f, 0.f, 0.f};
    SB = __builtin_amdgcn_mfma_f32_16x16x32_bf16(kf0, qfB0, SB, 0, 0, 0);
    SB = __builtin_amdgcn_mfma_f32_16x16x32_bf16(kf1, qfB1, SB, 0, 0, 0);
    __builtin_amdgcn_s_setprio(0);

    // bias from LDS (bf16 -> f32) via live flag (attn13/15-validated)
    const bf16x4 braw = *(const bf16x4*)&biasL[sb * 64 + boff];
    const float b0 = bf2f(braw[0]), b1 = bf2f(braw[1]);
    const float b2 = bf2f(braw[2]), b3 = bf2f(braw[3]);
    float pA0 = fast_exp2(__builtin_fmaf(b0, liveA, SA[0]));
    float pA1 = fast_exp2(__builtin_fmaf(b1, liveA, SA[1]));
    float pA2 = fast_exp2(__builtin_fmaf(b2, liveA, SA[2]));
    float pA3 = fast_exp2(__builtin_fmaf(b3, liveA, SA[3]));
    lA += (pA0 + pA1) + (pA2 + pA3);
    float pB0 = fast_exp2(__builtin_fmaf(b0, liveB, SB[0]));
    float pB1 = fast_exp2(__builtin_fmaf(b1, liveB, SB[1]));
    float pB2 = fast_exp2(__builtin_fmaf(b2, liveB, SB[2]));
    float pB3 = fast_exp2(__builtin_fmaf(b3, liveB, SB[3]));
    lB += (pB0 + pB1) + (pB2 + pB3);

    union { bf16x4 v; __hip_bfloat162 h[2]; } pfA, pfB;
    pfA.h[0] = __float22bfloat162_rn(float2{pA0, pA1});
    pfA.h[1] = __float22bfloat162_rn(float2{pA2, pA3});
    pfB.h[0] = __float22bfloat162_rn(float2{pB0, pB1});
    pfB.h[1] = __float22bfloat162_rn(float2{pB2, pB3});

    __builtin_amdgcn_s_setprio(1);
    #pragma unroll
    for (int cb = 0; cb < 4; ++cb) {
      bf16x4 vf = *(const bf16x4*)&Vsc[(cb * 16 + l15) * KT_STRIDE + sgrp * 16 + g * 4];
      accA[cb] = mfma_16x16x16_bf16(vf, pfA.v, accA[cb]);
      accB[cb] = mfma_16x16x16_bf16(vf, pfB.v, accB[cb]);
    }
    __builtin_amdgcn_s_setprio(0);

    // T4 counted wait: tile sb+1 must be resident after this barrier.
    // Outstanding allowed = tiles {sb+2, sb+3} still in flight (FIFO vmcnt).
    if (sb + 3 < NT) {
      if (wv < 2) asm volatile("s_waitcnt vmcnt(6)" ::: "memory");
      else        asm volatile("s_waitcnt vmcnt(4)" ::: "memory");
    } else if (sb + 2 < NT) {
      if (wv < 2) asm volatile("s_waitcnt vmcnt(3)" ::: "memory");
      else        asm volatile("s_waitcnt vmcnt(2)" ::: "memory");
    } else {
      asm volatile("s_waitcnt vmcnt(0)" ::: "memory");
    }
    __builtin_amdgcn_s_barrier();
    ring = (ring + 1) & 3;
  }

  // ---- 4-partial combine over sgrp (two-round tree, R11-verbatim).
  float* scr = (float*)smem;
  {
    const int lb = lane * 36;
    if (sgrp >= 2) {
      float* base = scr + ((sgrp - 2) * 2 + tgrp) * 2304 + lb;
      #pragma unroll
      for (int cb = 0; cb < 4; ++cb) {
        *(f32x4*)&base[cb * 4] = accA[cb];
        *(f32x4*)&base[16 + cb * 4] = accB[cb];
      }
      base[32] = lA; base[33] = lB;
    }
    __syncthreads();
    if (sgrp < 2) {
      const float* base = scr + (sgrp * 2 + tgrp) * 2304 + lb;
      #pragma unroll
      for (int cb = 0; cb < 4; ++cb) {
        accA[cb] += *(const f32x4*)&base[cb * 4];
        accB[cb] += *(const f32x4*)&base[16 + cb * 4];
      }
      lA += base[32]; lB += base[33];
    }
    __syncthreads();
    if (sgrp == 1) {
      float* base = scr + tgrp * 2304 + lb;
      #pragma unroll
      for (int cb = 0; cb < 4; ++cb) {
        *(f32x4*)&base[cb * 4] = accA[cb];
        *(f32x4*)&base[16 + cb * 4] = accB[cb];
      }
      base[32] = lA; base[33] = lB;
    }
    __syncthreads();
    if (sgrp == 0) {
      const float* base = scr + tgrp * 2304 + lb;
      #pragma unroll
      for (int cb = 0; cb < 4; ++cb) {
        accA[cb] += *(const f32x4*)&base[cb * 4];
        accB[cb] += *(const f32x4*)&base[16 + cb * 4];
      }
      lA += base[32]; lB += base[33];

      lA += __shfl_xor(lA, 16, 64);
      lA += __shfl_xor(lA, 32, 64);
      lB += __shfl_xor(lB, 16, 64);
      lB += __shfl_xor(lB, 32, 64);
      const float ilA = 1.0f / lA;
      const float ilB = 1.0f / lB;
      const size_t out_base = (size_t)bh * 64 * T_LEN;
      #pragma unroll
      for (int cb = 0; cb < 4; ++cb) {
        #pragma unroll
        for (int r = 0; r < 4; ++r) {
          int c = cb * 16 + g * 4 + r;
          out[out_base + (size_t)c * T_LEN + tA] = accA[cb][r] * ilA;
          out[out_base + (size_t)c * T_LEN + tB] = accB[cb][r] * ilB;
        }
      }
    }
  }
}

// ---------------- fallback path (round-1 kernel, used if ws too small) ------------

__global__ __launch_bounds__(256) void attn_fb_kernel(const float* __restrict__ qkv,
                                                      const unsigned char* __restrict__ maskn,
                                                      float* __restrict__ out) {
  __shared__ __align__(16) short Kt[QBLK * KT_STRIDE];
  __shared__ __align__(16) short Vs[64 * KT_STRIDE];
  __shared__ __align__(16) unsigned char Ms[T_LEN];

  const int tid  = threadIdx.x;
  const int lane = tid & 63;
  const int wv   = tid >> 6;
  const int l15  = lane & 15;
  const int g    = lane >> 4;

  const int bh = blockIdx.y;
  const int nb = bh >> 4;
  const int t0 = blockIdx.x * QBLK;

  const float* __restrict__ Qg = qkv + (size_t)bh * NROWS * T_LEN;
  const float* __restrict__ Kg = Qg + (size_t)64 * T_LEN;
  const float* __restrict__ Vg = Qg + (size_t)128 * T_LEN;

  {
    const uint2* src = (const uint2*)(maskn + (size_t)nb * T_LEN);
    ((uint2*)Ms)[tid] = src[tid];
  }
  {
    const int c2 = (tid >> 6) * 2;
    const int s  = tid & 63;
    #pragma unroll
    for (int p = 0; p < 8; ++p) {
      int c = p * 8 + c2;
      float f0 = Qg[(size_t)c * T_LEN + t0 + s] * 0.125f;
      float f1 = Qg[(size_t)(c + 1) * T_LEN + t0 + s] * 0.125f;
      *(unsigned*)&Kt[s * KT_STRIDE + c] = pack2(f0, f1);
    }
  }
  __syncthreads();

  bf16x8 qf0 = *(const bf16x8*)&Kt[(wv * 16 + l15) * KT_STRIDE + g * 8];
  bf16x8 qf1 = *(const bf16x8*)&Kt[(wv * 16 + l15) * KT_STRIDE + 32 + g * 8];
  const int t_lane = t0 + wv * 16 + l15;
  const bool invt = (Ms[t_lane] == 0);

  f32x4 acc[4];
  #pragma unroll
  for (int i = 0; i < 4; ++i) acc[i] = (f32x4){0.f, 0.f, 0.f, 0.f};
  float m_run = -3.0e38f;
  float l_run = 0.0f;

  for (int sb = 0; sb < NT; ++sb) {
    const int s0 = sb * 64;
    __syncthreads();
    {
      const int c2 = (tid >> 6) * 2;
      const int s  = tid & 63;
      #pragma unroll
      for (int p = 0; p < 8; ++p) {
        int c = p * 8 + c2;
        float f0 = Kg[(size_t)c * T_LEN + s0 + s];
        float f1 = Kg[(size_t)(c + 1) * T_LEN + s0 + s];
        *(unsigned*)&Kt[s * KT_STRIDE + c] = pack2(f0, f1);
      }
    }
    {
      const int cv = (tid >> 5);
      const int s2 = tid & 31;
      #pragma unroll
      for (int p = 0; p < 8; ++p) {
        int c = p * 8 + cv;
        float2 f = *(const float2*)&Vg[(size_t)c * T_LEN + s0 + 2 * s2];
        *(unsigned*)&Vs[c * KT_STRIDE + 2 * s2] = pack2(f.x, f.y);
      }
    }
    __syncthreads();

    #pragma unroll
    for (int st = 0; st < 4; ++st) {
      const int srow = st * 16 + l15;
      bf16x8 kf0 = *(const bf16x8*)&Kt[srow * KT_STRIDE + g * 8];
      bf16x8 kf1 = *(const bf16x8*)&Kt[srow * KT_STRIDE + 32 + g * 8];
      f32x4 S = (f32x4){0.f, 0.f, 0.f, 0.f};
      S = __builtin_amdgcn_mfma_f32_16x16x32_bf16(kf0, qf0, S, 0, 0, 0);
      S = __builtin_amdgcn_mfma_f32_16x16x32_bf16(kf1, qf1, S, 0, 0, 0);

      const unsigned m4 = *(const unsigned*)&Ms[s0 + st * 16 + g * 4];
      float vals[4];
      #pragma unroll
      for (int r = 0; r < 4; ++r) {
        float x = ((m4 >> (8 * r)) & 0xffu) ? S[r] : -1.0e30f;
        vals[r] = invt ? 0.0f : x;
      }
      float pm = fmaxf(fmaxf(vals[0], vals[1]), fmaxf(vals[2], vals[3]));
      pm = fmaxf(pm, __shfl_xor(pm, 16, 64));
      pm = fmaxf(pm, __shfl_xor(pm, 32, 64));
      const float newm = fmaxf(m_run, pm);
      const float alpha = fast_exp2((m_run - newm) * 1.44269504f);
      float p0 = fast_exp2((vals[0] - newm) * 1.44269504f);
      float p1 = fast_exp2((vals[1] - newm) * 1.44269504f);
      float p2 = fast_exp2((vals[2] - newm) * 1.44269504f);
      float p3 = fast_exp2((vals[3] - newm) * 1.44269504f);
      float ps = (p0 + p1) + (p2 + p3);
      ps += __shfl_xor(ps, 16, 64);
      ps += __shfl_xor(ps, 32, 64);
      l_run = l_run * alpha + ps;
      m_run = newm;
      if (__any(alpha < 1.0f)) {
        #pragma unroll
        for (int cb = 0; cb < 4; ++cb)
          #pragma unroll
          for (int r = 0; r < 4; ++r) acc[cb][r] *= alpha;
      }
      bf16x4 pf;
      pf[0] = (short)f2bf(p0); pf[1] = (short)f2bf(p1);
      pf[2] = (short)f2bf(p2); pf[3] = (short)f2bf(p3);
      #pragma unroll
      for (int cb = 0; cb < 4; ++cb) {
        bf16x4 vf = *(const bf16x4*)&Vs[(cb * 16 + l15) * KT_STRIDE + st * 16 + g * 4];
        acc[cb] = mfma_16x16x16_bf16(vf, pf, acc[cb]);
      }
    }
  }

  const float il = 1.0f / l_run;
  const size_t out_base = (size_t)bh * 64 * T_LEN;
  #pragma unroll
  for (int cb = 0; cb < 4; ++cb) {
    #pragma unroll
    for (int r = 0; r < 4; ++r) {
      int c = cb * 16 + g * 4 + r;
      out[out_base + (size_t)c * T_LEN + t_lane] = acc[cb][r] * il;
    }
  }
}

// ---------------- launch ----------------

extern "C" void kernel_launch(void* const* d_in, const int* in_sizes, int n_in,
                              void* d_out, int out_size, void* d_ws, size_t ws_size,
                              hipStream_t stream) {
  (void)n_in; (void)out_size;
  const float* qkv = (const float*)d_in[0];
  const unsigned char* mraw = (const unsigned char*)d_in[1];
  float* out = (float*)d_out;
  const int mask_elems = in_sizes[1];   // 2*2048

  // ws layout: qtg(8 MB) | ktg tiles(9 MB) | vtg tiles(9 MB) | bias((mask_elems+2048)*4)
  const size_t QSZ = (size_t)NBH * T_LEN * 64 * sizeof(short);          // 8388608
  const size_t TSZ = (size_t)NBH * 32 * TILE_ELEMS * sizeof(short);     // 9437184
  const size_t BSZ = (size_t)(mask_elems + T_LEN) * sizeof(float);
  const size_t need = QSZ + 2 * TSZ + BSZ;
  if (ws_size >= need) {
    short* qtg = (short*)d_ws;
    short* ktg = (short*)((char*)d_ws + QSZ);
    short* vtg = (short*)((char*)d_ws + QSZ + TSZ);
    float* bias = (float*)((char*)d_ws + QSZ + 2 * TSZ);
    prep12_kernel<<<dim3(32, NBH, 4), 256, 0, stream>>>(qkv, mraw, qtg, ktg, vtg,
                                                        bias, mask_elems);
    attn16_kernel<<<dim3(NBH * 32), 512, 0, stream>>>(qtg, ktg, vtg, bias, out);
  } else {
    unsigned char* maskn = (unsigned char*)d_ws;
    nm_kernel<<<(mask_elems + 255) / 256, 256, 0, stream>>>(mraw, maskn, mask_elems);
    attn_fb_kernel<<<dim3(T_LEN / 64, NBH), 256, 0, stream>>>(qkv, maskn, out);
  }
}

// Round 17
// 76.726 us; speedup vs baseline: 2.7588x; 1.0381x over previous
//
#include <hip/hip_runtime.h>
#include <hip/hip_bf16.h>
#include <stdint.h>

namespace {

constexpr int T_LEN = 2048;
constexpr int NROWS = 192;       // 3*64 rows per head
constexpr int QBLK  = 64;
constexpr int NBH   = 32;        // 2 batches * 16 heads
constexpr int KT_STRIDE = 72;    // padded row stride (bf16 elems) — R1/R3-validated
constexpr int TILE_ELEMS = 64 * KT_STRIDE;   // 4608 elems = 9216 B per 64-tile
constexpr int TILE_BYTES = TILE_ELEMS * 2;   // 9216 B
constexpr int NT = T_LEN / 64;               // 32 tiles

typedef float f32x4 __attribute__((ext_vector_type(4)));
typedef short bf16x8 __attribute__((ext_vector_type(8)));
typedef short bf16x4 __attribute__((ext_vector_type(4)));

__device__ __forceinline__ unsigned short f2bf(float f) {
  union { float f; unsigned u; } v; v.f = f;
  unsigned r = v.u + 0x7fffu + ((v.u >> 16) & 1u);   // RNE
  return (unsigned short)(r >> 16);
}
__device__ __forceinline__ unsigned pack2(float a, float b) {
  return (unsigned)f2bf(a) | ((unsigned)f2bf(b) << 16);
}
__device__ __forceinline__ float bf2f(short s) {
  union { unsigned u; float f; } v;
  v.u = ((unsigned)(unsigned short)s) << 16;
  return v.f;
}
__device__ __forceinline__ float fast_exp2(float x) {
#if __has_builtin(__builtin_amdgcn_exp2f)
  return __builtin_amdgcn_exp2f(x);
#else
  return exp2f(x);
#endif
}
__device__ __forceinline__ f32x4 mfma_16x16x16_bf16(bf16x4 a, bf16x4 b, f32x4 c) {
#if __has_builtin(__builtin_amdgcn_mfma_f32_16x16x16bf16_1k)
  return __builtin_amdgcn_mfma_f32_16x16x16bf16_1k(a, b, c, 0, 0, 0);
#else
  asm("v_mfma_f32_16x16x16_bf16 %0, %1, %2, %0" : "+v"(c) : "v"(a), "v"(b));
  return c;
#endif
}
// Async global->LDS DMA, 16B per lane: LDS dest = wave-uniform base + lane*16.
__device__ __forceinline__ void gload_lds16(const void* g, void* l) {
  __builtin_amdgcn_global_load_lds(
      (const __attribute__((address_space(1))) unsigned int*)g,
      (__attribute__((address_space(3))) unsigned int*)l, 16, 0, 0);
}

} // namespace

// Normalize mask to uint8 (fallback path). Stride detect via guaranteed-true mask[0][1].
__global__ void nm_kernel(const unsigned char* __restrict__ raw,
                          unsigned char* __restrict__ outm, int n) {
  int stride = (raw[1] != 0) ? 1 : ((raw[4] != 0) ? 4 : 8);
  int i = blockIdx.x * blockDim.x + threadIdx.x;
  if (i < n) outm[i] = (raw[(size_t)i * stride] != 0) ? 1 : 0;
}

// ---------------- merged prepass (R12-R16-validated): ONE launch -------------------
__global__ __launch_bounds__(256) void prep12_kernel(const float* __restrict__ qkv,
                                                     const unsigned char* __restrict__ mraw,
                                                     short* __restrict__ qtg,
                                                     short* __restrict__ ktg,
                                                     short* __restrict__ vtg,
                                                     float* __restrict__ bias,
                                                     int mask_elems) {
  const int z  = blockIdx.z;
  const int bh = blockIdx.y;
  const int bx = blockIdx.x;
  const int t  = threadIdx.x;

  if (z >= 2) {
    int cid = ((bh * 64) + (z - 2) * 32 + bx) * 256 + t;
    int bh2 = cid >> 14;
    int rem = cid & 16383;
    int c = rem >> 8;
    int cg = rem & 255;
    int grp = cg >> 3, jin = cg & 7;
    const float* src = qkv + (size_t)bh2 * NROWS * T_LEN + (size_t)(128 + c) * T_LEN + cg * 8;
    float4 a = *(const float4*)src;
    float4 b = *(const float4*)(src + 4);
    bf16x4 o0, o1;
    o0[0] = (short)f2bf(a.x); o0[1] = (short)f2bf(a.y);
    o0[2] = (short)f2bf(a.z); o0[3] = (short)f2bf(a.w);
    o1[0] = (short)f2bf(b.x); o1[1] = (short)f2bf(b.y);
    o1[2] = (short)f2bf(b.z); o1[3] = (short)f2bf(b.w);
    short* d = vtg + (size_t)(bh2 * 32 + grp) * TILE_ELEMS + c * KT_STRIDE + jin * 8;
    *(bf16x4*)d = o0;
    *(bf16x4*)(d + 4) = o1;
    if (z == 2 && bh == 0 && bx < 24) {
      int i = bx * 256 + t;
      int stride = (mraw[1] != 0) ? 1 : ((mraw[4] != 0) ? 4 : 8);
      if (i < mask_elems) bias[i] = (mraw[(size_t)i * stride] != 0) ? 0.0f : -1.0e30f;
      else if (i < mask_elems + T_LEN) bias[i] = 0.0f;
    }
    return;
  }

  __shared__ float tile[64][65];
  const int s0 = bx * 64;
  const float* src = qkv + (size_t)bh * NROWS * T_LEN + (size_t)z * 64 * T_LEN;
  const int c = t >> 2;
  #pragma unroll
  for (int p = 0; p < 4; ++p) {
    int col = (t & 3) * 4 + p * 16;
    float4 v = *(const float4*)&src[(size_t)c * T_LEN + s0 + col];
    tile[c][col] = v.x; tile[c][col + 1] = v.y;
    tile[c][col + 2] = v.z; tile[c][col + 3] = v.w;
  }
  __syncthreads();
  const int s = t & 63;
  float scale;
  if (z) {
    scale = 1.0f;
  } else {
    const int mstride = (mraw[1] != 0) ? 1 : ((mraw[4] != 0) ? 4 : 8);
    const int nb = bh >> 4;
    const bool live = mraw[((size_t)nb * T_LEN + s0 + s) * mstride] != 0;
    scale = live ? 0.18033688011112042f : 0.0f;   // 0.125*log2(e), 0 for masked t
  }
  #pragma unroll
  for (int p = 0; p < 2; ++p) {
    int jc = (t >> 6) * 2 + p;
    bf16x4 o0, o1;
    #pragma unroll
    for (int i = 0; i < 4; ++i) {
      o0[i] = (short)f2bf(tile[jc * 8 + i][s] * scale);
      o1[i] = (short)f2bf(tile[jc * 8 + 4 + i][s] * scale);
    }
    short* d = z
      ? (ktg + (size_t)(bh * 32 + bx) * TILE_ELEMS + s * KT_STRIDE + jc * 8)
      : (qtg + (size_t)bh * T_LEN * 64 + (size_t)(s0 + s) * 64 + jc * 8);
    *(bf16x4*)d = o0;
    *(bf16x4*)(d + 4) = o1;
  }
}

// ------ attn17: pair-tile iterations. Two independent tile chains per barrier
// interval (intra-wave ILP); barriers halve (16 vs 32). Issue tiles sb+2,sb+3
// early (T14), drain-to-0 at the barrier (fully covered by the 2-tile compute
// phase). Ring-4 LDS. All per-element math attn15/16-verbatim.

__global__ __launch_bounds__(512, 4) void attn17_kernel(const short* __restrict__ qtg,
                                                        const short* __restrict__ ktg,
                                                        const short* __restrict__ vtg,
                                                        const float* __restrict__ bias,
                                                        float* __restrict__ out) {
  // K ring [0,4)*TILE | V ring [4,8)*TILE | bias bf16 row = 77824 B (2 blocks/CU)
  __shared__ __align__(16) short smem[8 * TILE_ELEMS + T_LEN];

  const int tid  = threadIdx.x;
  const int lane = tid & 63;
  const int wv   = tid >> 6;    // 0..7
  const int sgrp = wv & 3;      // owns st = sgrp
  const int tgrp = wv >> 2;     // owns tw = {2*tgrp, 2*tgrp+1}
  const int l15  = lane & 15;
  const int g    = lane >> 4;

  int id = blockIdx.x;
  id = (id & 7) * 128 + (id >> 3);   // bijective XCD swizzle (bit-rotation)
  const int bh = id >> 5;
  const int t0 = (id & 31) * QBLK;
  const int nb = bh >> 4;

  const int tA = t0 + tgrp * 32 + l15;
  const int tB = tA + 16;

  // Q fragments (masked-t rows pre-zeroed by prep12)
  const short* Qbase = qtg + (size_t)bh * T_LEN * 64;
  const bf16x8 qfA0 = *(const bf16x8*)(Qbase + (size_t)tA * 64 + g * 8);
  const bf16x8 qfA1 = *(const bf16x8*)(Qbase + (size_t)tA * 64 + 32 + g * 8);
  const bf16x8 qfB0 = *(const bf16x8*)(Qbase + (size_t)tB * 64 + g * 8);
  const bf16x8 qfB1 = *(const bf16x8*)(Qbase + (size_t)tB * 64 + 32 + g * 8);

  // live flags (masked t -> 0 -> bias nulled -> S=0 -> p=1 uniform)
  const float liveA = (bias[(size_t)nb * T_LEN + tA] == 0.0f) ? 1.0f : 0.0f;
  const float liveB = (bias[(size_t)nb * T_LEN + tB] == 0.0f) ? 1.0f : 0.0f;

  char* KtL = (char*)smem;
  char* VsL = (char*)smem + 4 * TILE_BYTES;
  short* biasL = smem + 8 * TILE_ELEMS;

  // stage bias row to LDS as bf16 (512 thr x 4 elems)
  {
    f32x4 bv = *(const f32x4*)&bias[(size_t)nb * T_LEN + tid * 4];
    union { bf16x4 v; __hip_bfloat162 h[2]; } bb;
    bb.h[0] = __float22bfloat162_rn(float2{bv[0], bv[1]});
    bb.h[1] = __float22bfloat162_rn(float2{bv[2], bv[3]});
    *(bf16x4*)&biasL[tid * 4] = bb.v;
  }

  const char* __restrict__ kt0 = (const char*)(ktg + (size_t)bh * 32 * TILE_ELEMS);
  const char* __restrict__ vt0 = (const char*)(vtg + (size_t)bh * 32 * TILE_ELEMS);

  // per-tile DMA: waves 0,1 issue 3 ops; waves 2-7 issue 2 ops.
  auto ISSUE = [&](int j, int r) {
    const char* ks = kt0 + (size_t)j * TILE_BYTES;
    const char* vs = vt0 + (size_t)j * TILE_BYTES;
    char* kd = KtL + r * TILE_BYTES;
    char* vd = VsL + r * TILE_BYTES;
    gload_lds16(ks + wv * 1024 + lane * 16, kd + wv * 1024);
    gload_lds16(vs + wv * 1024 + lane * 16, vd + wv * 1024);
    if (wv == 0) gload_lds16(ks + 8192 + lane * 16, kd + 8192);
    if (wv == 1) gload_lds16(vs + 8192 + lane * 16, vd + 8192);
  };

  f32x4 accA[4], accB[4];
  #pragma unroll
  for (int i = 0; i < 4; ++i) { accA[i] = (f32x4){0.f,0.f,0.f,0.f}; accB[i] = accA[i]; }
  float lA = 0.0f, lB = 0.0f;

  const int koff = (sgrp * 16 + l15) * KT_STRIDE;
  const int boff = sgrp * 16 + g * 4;

  // one tile's full compute (QK -> softmax -> PV), slot is an LDS address offset
  auto COMPUTE = [&](int slot, int sbi) {
    const short* Ktc = (const short*)(KtL + slot * TILE_BYTES);
    const short* Vsc = (const short*)(VsL + slot * TILE_BYTES);

    bf16x8 kf0 = *(const bf16x8*)&Ktc[koff + g * 8];
    bf16x8 kf1 = *(const bf16x8*)&Ktc[koff + 32 + g * 8];

    __builtin_amdgcn_s_setprio(1);
    f32x4 SA = (f32x4){0.f, 0.f, 0.f, 0.f};
    SA = __builtin_amdgcn_mfma_f32_16x16x32_bf16(kf0, qfA0, SA, 0, 0, 0);
    SA = __builtin_amdgcn_mfma_f32_16x16x32_bf16(kf1, qfA1, SA, 0, 0, 0);
    f32x4 SB = (f32x4){0.f, 0.f, 0.f, 0.f};
    SB = __builtin_amdgcn_mfma_f32_16x16x32_bf16(kf0, qfB0, SB, 0, 0, 0);
    SB = __builtin_amdgcn_mfma_f32_16x16x32_bf16(kf1, qfB1, SB, 0, 0, 0);
    __builtin_amdgcn_s_setprio(0);

    const bf16x4 braw = *(const bf16x4*)&biasL[sbi * 64 + boff];
    const float b0 = bf2f(braw[0]), b1 = bf2f(braw[1]);
    const float b2 = bf2f(braw[2]), b3 = bf2f(braw[3]);
    float pA0 = fast_exp2(__builtin_fmaf(b0, liveA, SA[0]));
    float pA1 = fast_exp2(__builtin_fmaf(b1, liveA, SA[1]));
    float pA2 = fast_exp2(__builtin_fmaf(b2, liveA, SA[2]));
    float pA3 = fast_exp2(__builtin_fmaf(b3, liveA, SA[3]));
    lA += (pA0 + pA1) + (pA2 + pA3);
    float pB0 = fast_exp2(__builtin_fmaf(b0, liveB, SB[0]));
    float pB1 = fast_exp2(__builtin_fmaf(b1, liveB, SB[1]));
    float pB2 = fast_exp2(__builtin_fmaf(b2, liveB, SB[2]));
    float pB3 = fast_exp2(__builtin_fmaf(b3, liveB, SB[3]));
    lB += (pB0 + pB1) + (pB2 + pB3);

    union { bf16x4 v; __hip_bfloat162 h[2]; } pfA, pfB;
    pfA.h[0] = __float22bfloat162_rn(float2{pA0, pA1});
    pfA.h[1] = __float22bfloat162_rn(float2{pA2, pA3});
    pfB.h[0] = __float22bfloat162_rn(float2{pB0, pB1});
    pfB.h[1] = __float22bfloat162_rn(float2{pB2, pB3});

    __builtin_amdgcn_s_setprio(1);
    #pragma unroll
    for (int cb = 0; cb < 4; ++cb) {
      bf16x4 vf = *(const bf16x4*)&Vsc[(cb * 16 + l15) * KT_STRIDE + sgrp * 16 + g * 4];
      accA[cb] = mfma_16x16x16_bf16(vf, pfA.v, accA[cb]);
      accB[cb] = mfma_16x16x16_bf16(vf, pfB.v, accB[cb]);
    }
    __builtin_amdgcn_s_setprio(0);
  };

  // prologue: tiles 0,1 resident before the first pair
  ISSUE(0, 0);
  ISSUE(1, 1);
  asm volatile("s_waitcnt vmcnt(0) lgkmcnt(0)" ::: "memory");
  __builtin_amdgcn_s_barrier();

  int ring = 0;
  for (int sb = 0; sb < NT; sb += 2) {
    // early-issue next pair; its latency hides under this pair's compute (T14)
    if (sb + 2 < NT) {
      ISSUE(sb + 2, (ring + 2) & 3);
      ISSUE(sb + 3, (ring + 3) & 3);
    }
    // two independent tile chains: compiler interleaves (only acc serializes)
    COMPUTE(ring, sb);
    COMPUTE((ring + 1) & 3, sb + 1);

    asm volatile("s_waitcnt vmcnt(0)" ::: "memory");
    __builtin_amdgcn_s_barrier();
    ring = (ring + 2) & 3;
  }

  // ---- 4-partial combine over sgrp (two-round tree, R11-verbatim).
  float* scr = (float*)smem;
  {
    const int lb = lane * 36;
    if (sgrp >= 2) {
      float* base = scr + ((sgrp - 2) * 2 + tgrp) * 2304 + lb;
      #pragma unroll
      for (int cb = 0; cb < 4; ++cb) {
        *(f32x4*)&base[cb * 4] = accA[cb];
        *(f32x4*)&base[16 + cb * 4] = accB[cb];
      }
      base[32] = lA; base[33] = lB;
    }
    __syncthreads();
    if (sgrp < 2) {
      const float* base = scr + (sgrp * 2 + tgrp) * 2304 + lb;
      #pragma unroll
      for (int cb = 0; cb < 4; ++cb) {
        accA[cb] += *(const f32x4*)&base[cb * 4];
        accB[cb] += *(const f32x4*)&base[16 + cb * 4];
      }
      lA += base[32]; lB += base[33];
    }
    __syncthreads();
    if (sgrp == 1) {
      float* base = scr + tgrp * 2304 + lb;
      #pragma unroll
      for (int cb = 0; cb < 4; ++cb) {
        *(f32x4*)&base[cb * 4] = accA[cb];
        *(f32x4*)&base[16 + cb * 4] = accB[cb];
      }
      base[32] = lA; base[33] = lB;
    }
    __syncthreads();
    if (sgrp == 0) {
      const float* base = scr + tgrp * 2304 + lb;
      #pragma unroll
      for (int cb = 0; cb < 4; ++cb) {
        accA[cb] += *(const f32x4*)&base[cb * 4];
        accB[cb] += *(const f32x4*)&base[16 + cb * 4];
      }
      lA += base[32]; lB += base[33];

      lA += __shfl_xor(lA, 16, 64);
      lA += __shfl_xor(lA, 32, 64);
      lB += __shfl_xor(lB, 16, 64);
      lB += __shfl_xor(lB, 32, 64);
      const float ilA = 1.0f / lA;
      const float ilB = 1.0f / lB;
      const size_t out_base = (size_t)bh * 64 * T_LEN;
      #pragma unroll
      for (int cb = 0; cb < 4; ++cb) {
        #pragma unroll
        for (int r = 0; r < 4; ++r) {
          int c = cb * 16 + g * 4 + r;
          out[out_base + (size_t)c * T_LEN + tA] = accA[cb][r] * ilA;
          out[out_base + (size_t)c * T_LEN + tB] = accB[cb][r] * ilB;
        }
      }
    }
  }
}

// ---------------- fallback path (round-1 kernel, used if ws too small) ------------

__global__ __launch_bounds__(256) void attn_fb_kernel(const float* __restrict__ qkv,
                                                      const unsigned char* __restrict__ maskn,
                                                      float* __restrict__ out) {
  __shared__ __align__(16) short Kt[QBLK * KT_STRIDE];
  __shared__ __align__(16) short Vs[64 * KT_STRIDE];
  __shared__ __align__(16) unsigned char Ms[T_LEN];

  const int tid  = threadIdx.x;
  const int lane = tid & 63;
  const int wv   = tid >> 6;
  const int l15  = lane & 15;
  const int g    = lane >> 4;

  const int bh = blockIdx.y;
  const int nb = bh >> 4;
  const int t0 = blockIdx.x * QBLK;

  const float* __restrict__ Qg = qkv + (size_t)bh * NROWS * T_LEN;
  const float* __restrict__ Kg = Qg + (size_t)64 * T_LEN;
  const float* __restrict__ Vg = Qg + (size_t)128 * T_LEN;

  {
    const uint2* src = (const uint2*)(maskn + (size_t)nb * T_LEN);
    ((uint2*)Ms)[tid] = src[tid];
  }
  {
    const int c2 = (tid >> 6) * 2;
    const int s  = tid & 63;
    #pragma unroll
    for (int p = 0; p < 8; ++p) {
      int c = p * 8 + c2;
      float f0 = Qg[(size_t)c * T_LEN + t0 + s] * 0.125f;
      float f1 = Qg[(size_t)(c + 1) * T_LEN + t0 + s] * 0.125f;
      *(unsigned*)&Kt[s * KT_STRIDE + c] = pack2(f0, f1);
    }
  }
  __syncthreads();

  bf16x8 qf0 = *(const bf16x8*)&Kt[(wv * 16 + l15) * KT_STRIDE + g * 8];
  bf16x8 qf1 = *(const bf16x8*)&Kt[(wv * 16 + l15) * KT_STRIDE + 32 + g * 8];
  const int t_lane = t0 + wv * 16 + l15;
  const bool invt = (Ms[t_lane] == 0);

  f32x4 acc[4];
  #pragma unroll
  for (int i = 0; i < 4; ++i) acc[i] = (f32x4){0.f, 0.f, 0.f, 0.f};
  float m_run = -3.0e38f;
  float l_run = 0.0f;

  for (int sb = 0; sb < NT; ++sb) {
    const int s0 = sb * 64;
    __syncthreads();
    {
      const int c2 = (tid >> 6) * 2;
      const int s  = tid & 63;
      #pragma unroll
      for (int p = 0; p < 8; ++p) {
        int c = p * 8 + c2;
        float f0 = Kg[(size_t)c * T_LEN + s0 + s];
        float f1 = Kg[(size_t)(c + 1) * T_LEN + s0 + s];
        *(unsigned*)&Kt[s * KT_STRIDE + c] = pack2(f0, f1);
      }
    }
    {
      const int cv = (tid >> 5);
      const int s2 = tid & 31;
      #pragma unroll
      for (int p = 0; p < 8; ++p) {
        int c = p * 8 + cv;
        float2 f = *(const float2*)&Vg[(size_t)c * T_LEN + s0 + 2 * s2];
        *(unsigned*)&Vs[c * KT_STRIDE + 2 * s2] = pack2(f.x, f.y);
      }
    }
    __syncthreads();

    #pragma unroll
    for (int st = 0; st < 4; ++st) {
      const int srow = st * 16 + l15;
      bf16x8 kf0 = *(const bf16x8*)&Kt[srow * KT_STRIDE + g * 8];
      bf16x8 kf1 = *(const bf16x8*)&Kt[srow * KT_STRIDE + 32 + g * 8];
      f32x4 S = (f32x4){0.f, 0.f, 0.f, 0.f};
      S = __builtin_amdgcn_mfma_f32_16x16x32_bf16(kf0, qf0, S, 0, 0, 0);
      S = __builtin_amdgcn_mfma_f32_16x16x32_bf16(kf1, qf1, S, 0, 0, 0);

      const unsigned m4 = *(const unsigned*)&Ms[s0 + st * 16 + g * 4];
      float vals[4];
      #pragma unroll
      for (int r = 0; r < 4; ++r) {
        float x = ((m4 >> (8 * r)) & 0xffu) ? S[r] : -1.0e30f;
        vals[r] = invt ? 0.0f : x;
      }
      float pm = fmaxf(fmaxf(vals[0], vals[1]), fmaxf(vals[2], vals[3]));
      pm = fmaxf(pm, __shfl_xor(pm, 16, 64));
      pm = fmaxf(pm, __shfl_xor(pm, 32, 64));
      const float newm = fmaxf(m_run, pm);
      const float alpha = fast_exp2((m_run - newm) * 1.44269504f);
      float p0 = fast_exp2((vals[0] - newm) * 1.44269504f);
      float p1 = fast_exp2((vals[1] - newm) * 1.44269504f);
      float p2 = fast_exp2((vals[2] - newm) * 1.44269504f);
      float p3 = fast_exp2((vals[3] - newm) * 1.44269504f);
      float ps = (p0 + p1) + (p2 + p3);
      ps += __shfl_xor(ps, 16, 64);
      ps += __shfl_xor(ps, 32, 64);
      l_run = l_run * alpha + ps;
      m_run = newm;
      if (__any(alpha < 1.0f)) {
        #pragma unroll
        for (int cb = 0; cb < 4; ++cb)
          #pragma unroll
          for (int r = 0; r < 4; ++r) acc[cb][r] *= alpha;
      }
      bf16x4 pf;
      pf[0] = (short)f2bf(p0); pf[1] = (short)f2bf(p1);
      pf[2] = (short)f2bf(p2); pf[3] = (short)f2bf(p3);
      #pragma unroll
      for (int cb = 0; cb < 4; ++cb) {
        bf16x4 vf = *(const bf16x4*)&Vs[(cb * 16 + l15) * KT_STRIDE + st * 16 + g * 4];
        acc[cb] = mfma_16x16x16_bf16(vf, pf, acc[cb]);
      }
    }
  }

  const float il = 1.0f / l_run;
  const size_t out_base = (size_t)bh * 64 * T_LEN;
  #pragma unroll
  for (int cb = 0; cb < 4; ++cb) {
    #pragma unroll
    for (int r = 0; r < 4; ++r) {
      int c = cb * 16 + g * 4 + r;
      out[out_base + (size_t)c * T_LEN + t_lane] = acc[cb][r] * il;
    }
  }
}

// ---------------- launch ----------------

extern "C" void kernel_launch(void* const* d_in, const int* in_sizes, int n_in,
                              void* d_out, int out_size, void* d_ws, size_t ws_size,
                              hipStream_t stream) {
  (void)n_in; (void)out_size;
  const float* qkv = (const float*)d_in[0];
  const unsigned char* mraw = (const unsigned char*)d_in[1];
  float* out = (float*)d_out;
  const int mask_elems = in_sizes[1];   // 2*2048

  // ws layout: qtg(8 MB) | ktg tiles(9 MB) | vtg tiles(9 MB) | bias((mask_elems+2048)*4)
  const size_t QSZ = (size_t)NBH * T_LEN * 64 * sizeof(short);          // 8388608
  const size_t TSZ = (size_t)NBH * 32 * TILE_ELEMS * sizeof(short);     // 9437184
  const size_t BSZ = (size_t)(mask_elems + T_LEN) * sizeof(float);
  const size_t need = QSZ + 2 * TSZ + BSZ;
  if (ws_size >= need) {
    short* qtg = (short*)d_ws;
    short* ktg = (short*)((char*)d_ws + QSZ);
    short* vtg = (short*)((char*)d_ws + QSZ + TSZ);
    float* bias = (float*)((char*)d_ws + QSZ + 2 * TSZ);
    prep12_kernel<<<dim3(32, NBH, 4), 256, 0, stream>>>(qkv, mraw, qtg, ktg, vtg,
                                                        bias, mask_elems);
    attn17_kernel<<<dim3(NBH * 32), 512, 0, stream>>>(qtg, ktg, vtg, bias, out);
  } else {
    unsigned char* maskn = (unsigned char*)d_ws;
    nm_kernel<<<(mask_elems + 255) / 256, 256, 0, stream>>>(mraw, maskn, mask_elems);
    attn_fb_kernel<<<dim3(T_LEN / 64, NBH), 256, 0, stream>>>(qkv, maskn, out);
  }
}